// Round 9
// baseline (761.736 us; speedup 1.0000x reference)
//
#include <hip/hip_runtime.h>
#include <math.h>

constexpr int Bq  = 8;
constexpr int NGq = 16384;
constexpr int Nq  = Bq * NGq;       // 131072 nodes
constexpr int Eq  = Nq * 16;        // 2097152 edges
constexpr int Eg  = Eq / 8;         // 262144 edges per graph

// ---------------------------------------------------------------------------
// Pack the four 64x64 weight matrices into paired-transposed layout:
// out2[p*64 + j] = { W[j][2p], W[j][2p+1] }  (float2)
// ---------------------------------------------------------------------------
__global__ void k_wt4(const float* __restrict__ A, const float* __restrict__ B,
                      const float* __restrict__ C, const float* __restrict__ D,
                      float* __restrict__ o) {
    const float* in = (blockIdx.x == 0) ? A : (blockIdx.x == 1) ? B
                     : (blockIdx.x == 2) ? C : D;
    float2* out = (float2*)(o + (size_t)blockIdx.x * 4096);
    int t = threadIdx.x;
    for (int i = t; i < 2048; i += 256) {
        int p = i >> 6, j = i & 63;
        out[i] = make_float2(in[j * 64 + 2 * p], in[j * 64 + 2 * p + 1]);
    }
}

// ---------------------------------------------------------------------------
// CSR build (by dst, storing src) — graph-per-XCD swizzled scatter
// ---------------------------------------------------------------------------
__global__ void k_cnt(const int* __restrict__ dst, int* __restrict__ cnt) {
    int blk = blockIdx.x;
    int g = blk & 7, c = blk >> 3;
    int e = g * Eg + c * 256 + threadIdx.x;
    atomicAdd(&cnt[dst[e]], 1);
}

__global__ void k_scan_a(const int* __restrict__ cnt, int* __restrict__ bsum) {
    __shared__ int s[4];
    int t = threadIdx.x;
    int v = cnt[blockIdx.x * 256 + t];
    for (int o = 32; o; o >>= 1) v += __shfl_xor(v, o);
    if ((t & 63) == 0) s[t >> 6] = v;
    __syncthreads();
    if (t == 0) bsum[blockIdx.x] = s[0] + s[1] + s[2] + s[3];
}

__global__ void k_scan_b(int* __restrict__ bsum) {
    __shared__ int s[512];
    int t = threadIdx.x;
    int own = bsum[t];
    s[t] = own;
    __syncthreads();
    for (int d = 1; d < 512; d <<= 1) {
        int v = (t >= d) ? s[t - d] : 0;
        __syncthreads();
        if (t >= d) s[t] += v;
        __syncthreads();
    }
    bsum[t] = s[t] - own;   // exclusive
}

__global__ void k_scan_c(const int* __restrict__ cnt, const int* __restrict__ bsum,
                         int* __restrict__ off, int* __restrict__ cursor) {
    __shared__ int s[4];
    int t = threadIdx.x, blk = blockIdx.x;
    int base = blk * 256;
    int v = cnt[base + t];
    int lane = t & 63, wv = t >> 6;
    int val = v;
    for (int o = 1; o < 64; o <<= 1) {
        int u = __shfl_up(val, o);
        if (lane >= o) val += u;
    }
    if (lane == 63) s[wv] = val;
    __syncthreads();
    int add = 0;
    for (int q = 0; q < wv; q++) add += s[q];
    int excl = val + add - v;
    int o0 = bsum[blk] + excl;
    off[base + t] = o0;
    cursor[base + t] = o0;
    if (blk == 0 && t == 0) off[Nq] = Eq;
}

__global__ void k_fill(const int* __restrict__ src, const int* __restrict__ dst,
                       int* __restrict__ cursor, int* __restrict__ csrc) {
    int blk = blockIdx.x;
    int g = blk & 7, c = blk >> 3;
    int e = g * Eg + c * 256 + threadIdx.x;
    int p = atomicAdd(&cursor[dst[e]], 1);
    if (p < Eq) csrc[p] = src[e];   // guard: keeps rocprof replay benign
}

// ---------------------------------------------------------------------------
// Round 1 SAGE (dim-2 input), fused conv + relu + topk-score. Wave per node.
// ---------------------------------------------------------------------------
__global__ void k_sage1(const float* __restrict__ x, const int* __restrict__ off,
                        const int* __restrict__ csrc,
                        const float* __restrict__ Wl, const float* __restrict__ bl,
                        const float* __restrict__ Wr, const float* __restrict__ wp,
                        float* __restrict__ out, float* __restrict__ score) {
    int blk = blockIdx.x;
    int g = blk & 7, i = blk >> 3;
    int wv = threadIdx.x >> 6, j = threadIdx.x & 63;
    int n = g * NGq + i * 4 + wv;
    int beg = off[n], end = off[n + 1];
    float2 xn = ((const float2*)x)[n];
    float s0 = 0.f, s1 = 0.f;
    for (int e = beg + j; e < end; e += 64) {
        float2 xv = ((const float2*)x)[csrc[e]];
        s0 += xv.x; s1 += xv.y;
    }
    for (int o = 32; o; o >>= 1) { s0 += __shfl_xor(s0, o); s1 += __shfl_xor(s1, o); }
    float c = fmaxf((float)(end - beg), 1.0f);
    float m0 = s0 / c, m1 = s1 / c;
    float v = Wl[2 * j] * m0 + Wl[2 * j + 1] * m1 + bl[j]
            + Wr[2 * j] * xn.x + Wr[2 * j + 1] * xn.y;
    v = fmaxf(v, 0.f);
    out[n * 64 + j] = v;
    float wvp = wp[j];
    float d = v * wvp, ww = wvp * wvp;
    for (int o = 32; o; o >>= 1) { d += __shfl_xor(d, o); ww += __shfl_xor(ww, o); }
    if (j == 0) score[n] = tanhf(d / sqrtf(ww));
}

// ---------------------------------------------------------------------------
// Per-graph top-k radix select — keys in registers (proven in R8)
// ---------------------------------------------------------------------------
template<int M>
__global__ void k_topk(const float* __restrict__ score, int* __restrict__ newpos,
                       int* __restrict__ perm) {
    constexpr int n = M * 1024;
    constexpr int k = n / 2;
    __shared__ unsigned hist[256];
    __shared__ unsigned sh_pfx, sh_msk, sh_rem;
    __shared__ int sh_eqtot, sh_ctr;
    __shared__ int wtot[16];
    __shared__ int runTie, runGt;
    int t = threadIdx.x, b = blockIdx.x;
    int base = b * n;
    int lane = t & 63, wv = t >> 6;

    unsigned kr[M];
#pragma unroll
    for (int i = 0; i < M; i++) {
        unsigned u = __float_as_uint(score[base + t + (i << 10)]);
        kr[i] = u ^ ((u >> 31) ? 0xFFFFFFFFu : 0x80000000u);
    }
    if (t < 256) hist[t] = 0;
    if (t == 0) { sh_pfx = 0; sh_msk = 0; sh_rem = (unsigned)k;
                  sh_eqtot = 0; sh_ctr = 0; runTie = 0; runGt = 0; }
    __syncthreads();

    for (int shift = 24; shift >= 0; shift -= 8) {
        unsigned pfx = sh_pfx, msk = sh_msk;
#pragma unroll
        for (int i = 0; i < M; i++)
            if ((kr[i] & msk) == pfx) atomicAdd(&hist[(kr[i] >> shift) & 255], 1u);
        __syncthreads();
        if (t < 64) {
            unsigned rem = sh_rem;
            unsigned c0 = hist[255 - (t * 4 + 0)];
            unsigned c1 = hist[255 - (t * 4 + 1)];
            unsigned c2 = hist[255 - (t * 4 + 2)];
            unsigned c3 = hist[255 - (t * 4 + 3)];
            unsigned s = c0 + c1 + c2 + c3;
            unsigned sc = s;
            for (int o = 1; o < 64; o <<= 1) {
                unsigned u = __shfl_up(sc, o);
                if (t >= o) sc += u;
            }
            unsigned run = sc - s;
            unsigned cc[4] = {c0, c1, c2, c3};
#pragma unroll
            for (int q = 0; q < 4; q++) {
                unsigned incl = run + cc[q];
                if (run < rem && incl >= rem) {
                    int bb = 255 - (t * 4 + q);
                    sh_rem = rem - run;
                    sh_pfx = pfx | ((unsigned)bb << shift);
                    sh_msk = msk | (255u << shift);
                }
                run = incl;
            }
        }
        __syncthreads();
        if (t < 256) hist[t] = 0;
        __syncthreads();
    }
    unsigned K = sh_pfx;
    int T = (int)sh_rem;

    int le = 0;
#pragma unroll
    for (int i = 0; i < M; i++) le += (kr[i] == K) ? 1 : 0;
    for (int o = 32; o; o >>= 1) le += __shfl_xor(le, o);
    if (lane == 0) atomicAdd(&sh_eqtot, le);
    __syncthreads();

    if (sh_eqtot == T) {
        // fast path: every tie kept; order-free atomic compaction
#pragma unroll
        for (int i = 0; i < M; i++) {
            int cur = base + t + (i << 10);
            bool kept = kr[i] >= K;
            unsigned long long mk = __ballot(kept);
            int pos = 0;
            if (mk) {
                int fl = __ffsll(mk) - 1;
                int bp = 0;
                if (lane == fl) bp = atomicAdd(&sh_ctr, __popcll(mk));
                bp = __shfl(bp, fl);
                pos = bp + __popcll(mk & ((1ull << lane) - 1ull));
            }
            if (kept && pos < k) {
                newpos[cur] = b * k + pos;
                perm[b * k + pos] = cur;
            } else newpos[cur] = -1;
        }
    } else {
        // ordered fallback (rare)
        for (int i = 0; i < M; i++) {
            unsigned key = kr[i];
            int gt = key > K ? 1 : 0;
            int eq = key == K ? 1 : 0;
            int val = (eq << 16) | gt;
            for (int o = 1; o < 64; o <<= 1) {
                int v = __shfl_up(val, o);
                if (lane >= o) val += v;
            }
            if (lane == 63) wtot[wv] = val;
            __syncthreads();
            int add = 0;
            for (int q = 0; q < 16; q++) if (q < wv) add += wtot[q];
            val += add;
            int eqIncl = val >> 16, gtIncl = val & 0xffff;
            int eqExcl = eqIncl - eq, gtExcl = gtIncl - gt;
            int kept = gt | (eq & ((runTie + eqExcl) < T ? 1 : 0));
            int cur = base + t + (i << 10);
            if (kept) {
                int selEqBefore = runTie + eqExcl; if (selEqBefore > T) selEqBefore = T;
                int nl = runGt + gtExcl + selEqBefore;
                if (nl < k) {
                    newpos[cur] = b * k + nl;
                    perm[b * k + nl] = cur;
                } else newpos[cur] = -1;
            } else newpos[cur] = -1;
            __syncthreads();
            if (t == 1023) { runTie += eqIncl; runGt += gtIncl; }
            __syncthreads();
        }
    }
}

// gather kept rows gated by score; compose cur->orig id. Graph-swizzled.
__global__ void k_compact(const float* __restrict__ hin, const float* __restrict__ score,
                          const int* __restrict__ perm, const int* __restrict__ orig_in,
                          int* __restrict__ orig_out, int first,
                          float* __restrict__ hout, int k) {
    int blk = blockIdx.x;
    int g = blk & 7, i = blk >> 3;
    int wv = threadIdx.x >> 6, j = threadIdx.x & 63;
    int nn = g * k + i * 4 + wv;
    int old = perm[nn];
    hout[nn * 64 + j] = hin[old * 64 + j] * score[old];
    if (j == 0) orig_out[nn] = first ? old : orig_in[old];
}

__global__ void k_map(const int* __restrict__ newpos, int* __restrict__ map, int first) {
    int i = blockIdx.x * blockDim.x + threadIdx.x;
    if (i >= Nq) return;
    if (first) map[i] = newpos[i];
    else { int m = map[i]; map[i] = (m >= 0) ? newpos[m] : -1; }
}

// ---------------------------------------------------------------------------
// Readout [max | mean] — two-stage, graph-swizzled
// ---------------------------------------------------------------------------
__global__ void k_readout_part(const float* __restrict__ h, float* __restrict__ part,
                               int k, int G) {
    __shared__ float smx[256], ssm[256];
    int blk = blockIdx.x;
    int b = blk & 7, g = blk >> 3;
    int rows = k / G;
    int t = threadIdx.x, j = t & 63, q = t >> 6;
    const float* basep = h + ((size_t)b * k + (size_t)g * rows) * 64;
    float mx = -3.0e38f, sm = 0.f;
    for (int i = q; i < rows; i += 4) {
        float v = basep[i * 64 + j];
        mx = fmaxf(mx, v); sm += v;
    }
    smx[t] = mx; ssm[t] = sm;
    __syncthreads();
    if (q == 0) {
        for (int r = 1; r < 4; r++) { mx = fmaxf(mx, smx[j + 64 * r]); sm += ssm[j + 64 * r]; }
        part[(b * G + g) * 128 + j] = mx;
        part[(b * G + g) * 128 + 64 + j] = sm;
    }
}

__global__ void k_readout_fin(const float* __restrict__ part, float* __restrict__ z,
                              int k, int G) {
    int i = blockIdx.x * blockDim.x + threadIdx.x;
    if (i >= 8 * 128) return;
    int b = i >> 7, j = i & 127;
    if (j < 64) {
        float mx = -3.0e38f;
        for (int g = 0; g < G; g++) mx = fmaxf(mx, part[(b * G + g) * 128 + j]);
        z[b * 128 + j] += mx;
    } else {
        float sm = 0.f;
        for (int g = 0; g < G; g++) sm += part[(b * G + g) * 128 + j];
        z[b * 128 + j] += sm / (float)k;
    }
}

// ---------------------------------------------------------------------------
// SAGE round 2: shuffle-broadcast gather (R6, proven) + paired-weight epilogue.
// ---------------------------------------------------------------------------
__global__ void k_sage_gather(const float* __restrict__ h, const int* __restrict__ off,
                              const int* __restrict__ csrc, const int* __restrict__ map,
                              const int* __restrict__ orig,
                              const float* __restrict__ WlP, const float* __restrict__ bl,
                              const float* __restrict__ WrP, const float* __restrict__ wp,
                              float* __restrict__ out, float* __restrict__ score, int ng) {
    __shared__ __align__(16) float sh[4][128];
    int blk = blockIdx.x;
    int g = blk & 7, i = blk >> 3;
    int wv = threadIdx.x >> 6, j = threadIdx.x & 63;
    int n = g * ng + i * 4 + wv;
    int o = orig[n];
    int beg = off[o], end = off[o + 1];
    float own = h[n * 64 + j];           // hoisted: overlaps edge resolution
    float acc = 0.f; int cnt = 0;
    for (int base = beg; base < end; base += 64) {
        int d = end - base; if (d > 64) d = 64;
        int cs = (j < d) ? map[csrc[base + j]] : -1;
        cnt += __popcll(__ballot(cs >= 0));
        int e = 0;
        for (; e + 8 <= d; e += 8) {
            int c0 = __shfl(cs, e),     c1 = __shfl(cs, e + 1);
            int c2 = __shfl(cs, e + 2), c3 = __shfl(cs, e + 3);
            int c4 = __shfl(cs, e + 4), c5 = __shfl(cs, e + 5);
            int c6 = __shfl(cs, e + 6), c7 = __shfl(cs, e + 7);
            float v0 = (c0 >= 0) ? h[c0 * 64 + j] : 0.f;
            float v1 = (c1 >= 0) ? h[c1 * 64 + j] : 0.f;
            float v2 = (c2 >= 0) ? h[c2 * 64 + j] : 0.f;
            float v3 = (c3 >= 0) ? h[c3 * 64 + j] : 0.f;
            float v4 = (c4 >= 0) ? h[c4 * 64 + j] : 0.f;
            float v5 = (c5 >= 0) ? h[c5 * 64 + j] : 0.f;
            float v6 = (c6 >= 0) ? h[c6 * 64 + j] : 0.f;
            float v7 = (c7 >= 0) ? h[c7 * 64 + j] : 0.f;
            acc += ((v0 + v1) + (v2 + v3)) + ((v4 + v5) + (v6 + v7));
        }
        for (; e + 4 <= d; e += 4) {
            int c0 = __shfl(cs, e),     c1 = __shfl(cs, e + 1);
            int c2 = __shfl(cs, e + 2), c3 = __shfl(cs, e + 3);
            float v0 = (c0 >= 0) ? h[c0 * 64 + j] : 0.f;
            float v1 = (c1 >= 0) ? h[c1 * 64 + j] : 0.f;
            float v2 = (c2 >= 0) ? h[c2 * 64 + j] : 0.f;
            float v3 = (c3 >= 0) ? h[c3 * 64 + j] : 0.f;
            acc += (v0 + v1) + (v2 + v3);
        }
        for (; e < d; e++) {
            int c0 = __shfl(cs, e);
            if (c0 >= 0) acc += h[c0 * 64 + j];
        }
    }
    // wave-private LDS staging — same-wave write->read, in-order on CDNA
    sh[wv][j] = acc / fmaxf((float)cnt, 1.0f);
    sh[wv][64 + j] = own;
    const float2* smp = (const float2*)sh[wv];
    const float2* w2l = (const float2*)WlP;
    const float2* w2r = (const float2*)WrP;
    float ax = bl[j], ay = 0.f;
#pragma unroll
    for (int q2 = 0; q2 < 32; q2++) {
        float2 m2 = smp[q2];
        float2 o2 = smp[32 + q2];
        float2 wl2 = w2l[q2 * 64 + j];
        float2 wr2 = w2r[q2 * 64 + j];
        ax += m2.x * wl2.x + o2.x * wr2.x;
        ay += m2.y * wl2.y + o2.y * wr2.y;
    }
    float v = fmaxf(ax + ay, 0.f);
    out[n * 64 + j] = v;
    float wvp = wp[j];
    float dd = v * wvp, ww = wvp * wvp;
    for (int o2 = 32; o2; o2 >>= 1) { dd += __shfl_xor(dd, o2); ww += __shfl_xor(ww, o2); }
    if (j == 0) score[n] = tanhf(dd / sqrtf(ww));
}

// ---------------------------------------------------------------------------
// GCN: xw = h @ W.T (paired weights) ; cnt+dis ; shuffle-broadcast gather
// ---------------------------------------------------------------------------
__global__ void k_xw(const float* __restrict__ h, const float* __restrict__ WP,
                     float* __restrict__ xw, int ntot) {
    int idx = blockIdx.x * blockDim.x + threadIdx.x;
    if (idx >= ntot * 64) return;
    int n = idx >> 6, j = idx & 63;
    const float2* hr = (const float2*)&h[n * 64];   // wave-uniform 8B loads
    const float2* w2 = (const float2*)WP;
    float ax = 0.f, ay = 0.f;
#pragma unroll
    for (int q2 = 0; q2 < 32; q2++) {
        float2 h2 = hr[q2];
        float2 ww = w2[q2 * 64 + j];
        ax += h2.x * ww.x; ay += h2.y * ww.y;
    }
    xw[idx] = ax + ay;
}

__global__ void k_cntdis(const int* __restrict__ off, const int* __restrict__ csrc,
                         const int* __restrict__ map, const int* __restrict__ orig,
                         float* __restrict__ dis, int ng) {
    int blk = blockIdx.x;
    int g = blk & 7, i = blk >> 3;
    int wv = threadIdx.x >> 6, j = threadIdx.x & 63;
    int n = g * ng + i * 4 + wv;
    int o = orig[n];
    int beg = off[o], end = off[o + 1];
    int c = 0;
    for (int base = beg; base < end; base += 64) {
        int d = end - base; if (d > 64) d = 64;
        int cs = (j < d) ? map[csrc[base + j]] : -1;
        c += __popcll(__ballot(cs >= 0));
    }
    if (j == 0) dis[n] = 1.0f / sqrtf(1.0f + (float)c);
}

__global__ void k_gcn_gather(const float* __restrict__ xw, const int* __restrict__ off,
                             const int* __restrict__ csrc, const int* __restrict__ map,
                             const int* __restrict__ orig, const float* __restrict__ dis,
                             const float* __restrict__ bb, const float* __restrict__ wp,
                             float* __restrict__ out, float* __restrict__ score, int ng) {
    int blk = blockIdx.x;
    int g = blk & 7, i = blk >> 3;
    int wv = threadIdx.x >> 6, j = threadIdx.x & 63;
    int n = g * ng + i * 4 + wv;
    int o = orig[n];
    int beg = off[o], end = off[o + 1];
    float dn = dis[n];
    float own = xw[n * 64 + j];
    float acc = 0.f;
    for (int base = beg; base < end; base += 64) {
        int d = end - base; if (d > 64) d = 64;
        int cs = -1; float dsv = 0.f;
        if (j < d) {
            int cc = map[csrc[base + j]];
            if (cc >= 0) { cs = cc; dsv = dis[cc]; }
        }
        int e = 0;
        for (; e + 8 <= d; e += 8) {
            int c0 = __shfl(cs, e),     c1 = __shfl(cs, e + 1);
            int c2 = __shfl(cs, e + 2), c3 = __shfl(cs, e + 3);
            int c4 = __shfl(cs, e + 4), c5 = __shfl(cs, e + 5);
            int c6 = __shfl(cs, e + 6), c7 = __shfl(cs, e + 7);
            float d0 = __shfl(dsv, e),     d1 = __shfl(dsv, e + 1);
            float d2 = __shfl(dsv, e + 2), d3 = __shfl(dsv, e + 3);
            float d4 = __shfl(dsv, e + 4), d5 = __shfl(dsv, e + 5);
            float d6 = __shfl(dsv, e + 6), d7 = __shfl(dsv, e + 7);
            float v0 = (c0 >= 0) ? xw[c0 * 64 + j] * d0 : 0.f;
            float v1 = (c1 >= 0) ? xw[c1 * 64 + j] * d1 : 0.f;
            float v2 = (c2 >= 0) ? xw[c2 * 64 + j] * d2 : 0.f;
            float v3 = (c3 >= 0) ? xw[c3 * 64 + j] * d3 : 0.f;
            float v4 = (c4 >= 0) ? xw[c4 * 64 + j] * d4 : 0.f;
            float v5 = (c5 >= 0) ? xw[c5 * 64 + j] * d5 : 0.f;
            float v6 = (c6 >= 0) ? xw[c6 * 64 + j] * d6 : 0.f;
            float v7 = (c7 >= 0) ? xw[c7 * 64 + j] * d7 : 0.f;
            acc += ((v0 + v1) + (v2 + v3)) + ((v4 + v5) + (v6 + v7));
        }
        for (; e + 4 <= d; e += 4) {
            int c0 = __shfl(cs, e),     c1 = __shfl(cs, e + 1);
            int c2 = __shfl(cs, e + 2), c3 = __shfl(cs, e + 3);
            float d0 = __shfl(dsv, e),     d1 = __shfl(dsv, e + 1);
            float d2 = __shfl(dsv, e + 2), d3 = __shfl(dsv, e + 3);
            float v0 = (c0 >= 0) ? xw[c0 * 64 + j] * d0 : 0.f;
            float v1 = (c1 >= 0) ? xw[c1 * 64 + j] * d1 : 0.f;
            float v2 = (c2 >= 0) ? xw[c2 * 64 + j] * d2 : 0.f;
            float v3 = (c3 >= 0) ? xw[c3 * 64 + j] * d3 : 0.f;
            acc += (v0 + v1) + (v2 + v3);
        }
        for (; e < d; e++) {
            int c0 = __shfl(cs, e);
            float d0 = __shfl(dsv, e);
            if (c0 >= 0) acc += xw[c0 * 64 + j] * d0;
        }
    }
    float v = acc * dn + own * dn * dn + bb[j];
    v = fmaxf(v, 0.f);
    out[n * 64 + j] = v;
    float wvp = wp[j];
    float dd = v * wvp, ww = wvp * wvp;
    for (int o2 = 32; o2; o2 >>= 1) { dd += __shfl_xor(dd, o2); ww += __shfl_xor(ww, o2); }
    if (j == 0) score[n] = tanhf(dd / sqrtf(ww));
}

// ---------------------------------------------------------------------------
// Final MLP + softmax: one block, all in LDS
// ---------------------------------------------------------------------------
__global__ void k_mlp(const float* __restrict__ z,
                      const float* __restrict__ Wa, const float* __restrict__ ba,
                      const float* __restrict__ Wb, const float* __restrict__ bb,
                      const float* __restrict__ Wc, const float* __restrict__ bc,
                      float* __restrict__ out) {
    __shared__ float sz[8 * 128];
    __shared__ float sa[8 * 128];
    __shared__ float sb[8 * 64];
    __shared__ float sc[8 * 256];
    int t = threadIdx.x;
    for (int i = t; i < 1024; i += 256) sz[i] = z[i];
    __syncthreads();
    for (int i = t; i < 1024; i += 256) {
        int b = i >> 7, o = i & 127;
        const float* wr = &Wa[o * 128];
        const float* zr = &sz[b * 128];
        float v = ba[o];
        for (int q = 0; q < 128; q++) v += zr[q] * wr[q];
        sa[i] = v > 0.f ? v : 0.f;
    }
    __syncthreads();
    for (int i = t; i < 512; i += 256) {
        int b = i >> 6, o = i & 63;
        const float* wr = &Wb[o * 128];
        const float* zr = &sa[b * 128];
        float v = bb[o];
        for (int q = 0; q < 128; q++) v += zr[q] * wr[q];
        sb[i] = v > 0.f ? v : 0.f;
    }
    __syncthreads();
    for (int i = t; i < 2048; i += 256) {
        int b = i >> 8, o = i & 255;
        const float* wr = &Wc[o * 64];
        const float* zr = &sb[b * 64];
        float v = bc[o];
        for (int q = 0; q < 64; q++) v += zr[q] * wr[q];
        sc[i] = v;
    }
    __syncthreads();
    int wv = t >> 6, ln = t & 63;
    for (int b = wv; b < 8; b += 4) {
        const float* row = &sc[b * 256];
        float m = -3.0e38f;
        for (int q = 0; q < 4; q++) m = fmaxf(m, row[ln + 64 * q]);
        for (int o = 32; o; o >>= 1) m = fmaxf(m, __shfl_xor(m, o));
        float s = 0.f;
        for (int q = 0; q < 4; q++) s += expf(row[ln + 64 * q] - m);
        for (int o = 32; o; o >>= 1) s += __shfl_xor(s, o);
        float inv = 1.f / s;
        for (int q = 0; q < 4; q++) out[b * 256 + ln + 64 * q] = expf(row[ln + 64 * q] - m) * inv;
    }
}

// ---------------------------------------------------------------------------
extern "C" void kernel_launch(void* const* d_in, const int* in_sizes, int n_in,
                              void* d_out, int out_size, void* d_ws, size_t ws_size,
                              hipStream_t stream) {
    const float* x   = (const float*)d_in[0];
    const int*   ei  = (const int*)d_in[1];
    const int* src = ei;
    const int* dst = ei + Eq;
    const float* Wl1 = (const float*)d_in[2];
    const float* bl1 = (const float*)d_in[3];
    const float* Wr1 = (const float*)d_in[4];
    const float* Wl2 = (const float*)d_in[5];
    const float* bl2 = (const float*)d_in[6];
    const float* Wr2 = (const float*)d_in[7];
    const float* W4  = (const float*)d_in[8];
    const float* b4  = (const float*)d_in[9];
    const float* W5  = (const float*)d_in[10];
    const float* b5  = (const float*)d_in[11];
    const float* wp1 = (const float*)d_in[12];
    const float* wp2 = (const float*)d_in[13];
    const float* wp4 = (const float*)d_in[14];
    const float* wp5 = (const float*)d_in[15];
    const float* Wa  = (const float*)d_in[16];
    const float* ba  = (const float*)d_in[17];
    const float* Wb  = (const float*)d_in[18];
    const float* bbv = (const float*)d_in[19];
    const float* Wc  = (const float*)d_in[20];
    const float* bc  = (const float*)d_in[21];
    float* out = (float*)d_out;

    const int N1 = Nq / 2, N2 = Nq / 4, N3 = Nq / 8, N4 = Nq / 16;

    // workspace layout (~64 MB)
    char* w = (char*)d_ws;
    float* hA    = (float*)w; w += (size_t)Nq * 64 * 4;        // 33.5 MB
    float* hB    = (float*)w; w += (size_t)N1 * 64 * 4;        // 16.8 MB
    int*   csrc  = (int*)w;   w += (size_t)Eq * 4;             //  8.4 MB
    int*   coff  = (int*)w;   w += (size_t)(Nq + 1) * 4;
    int*   cursor= (int*)w;   w += (size_t)Nq * 4;
    int*   cnt   = (int*)w;   w += (size_t)Nq * 4;
    float* dis   = (float*)w; w += (size_t)Nq * 4;
    float* score = (float*)w; w += (size_t)Nq * 4;
    int*   newpos= (int*)w;   w += (size_t)Nq * 4;
    int*   map   = (int*)w;   w += (size_t)Nq * 4;
    int*   perm  = (int*)w;   w += (size_t)Nq * 4;
    int*   origA = (int*)w;   w += (size_t)Nq * 4;
    int*   origB = (int*)w;   w += (size_t)Nq * 4;
    int*   bsum  = (int*)w;   w += 512 * 4;
    float* part  = (float*)w; w += (size_t)8 * 64 * 128 * 4;   // 256 KB
    float* z     = (float*)w; w += 1024 * 4;
    float* wT    = (float*)w; w += 4 * 4096 * 4;               // 64 KB
    float* WlP2 = wT, *WrP2 = wT + 4096, *W4P = wT + 8192, *W5P = wT + 12288;

    // ---- One-time: weight packing + CSR build
    k_wt4<<<4, 256, 0, stream>>>(Wl2, Wr2, W4, W5, wT);
    hipMemsetAsync(cnt, 0, (size_t)Nq * 4, stream);
    hipMemsetAsync(z, 0, 1024 * 4, stream);
    k_cnt<<<Eq / 256, 256, 0, stream>>>(dst, cnt);
    k_scan_a<<<512, 256, 0, stream>>>(cnt, bsum);
    k_scan_b<<<1, 512, 0, stream>>>(bsum);
    k_scan_c<<<512, 256, 0, stream>>>(cnt, bsum, coff, cursor);
    k_fill<<<Eq / 256, 256, 0, stream>>>(src, dst, cursor, csrc);

    // ---- Round 1: SAGE1(x) -> hA [Nq x 64], pool -> hB [N1 x 64]
    k_sage1<<<Nq / 4, 256, 0, stream>>>(x, coff, csrc, Wl1, bl1, Wr1, wp1, hA, score);
    k_topk<16><<<8, 1024, 0, stream>>>(score, newpos, perm);
    k_compact<<<N1 / 4, 256, 0, stream>>>(hA, score, perm, nullptr, origA, 1, hB, N1 / 8);
    k_map<<<Nq / 256, 256, 0, stream>>>(newpos, map, 1);
    k_readout_part<<<8 * 64, 256, 0, stream>>>(hB, part, NGq / 2, 64);
    k_readout_fin<<<4, 256, 0, stream>>>(part, z, NGq / 2, 64);

    // ---- Round 2: SAGE2(hB) -> hA [N1 x 64], pool -> hB [N2 x 64]
    k_sage_gather<<<N1 / 4, 256, 0, stream>>>(hB, coff, csrc, map, origA,
                                              WlP2, bl2, WrP2, wp2, hA, score, N1 / 8);
    k_topk<8><<<8, 1024, 0, stream>>>(score, newpos, perm);
    k_compact<<<N2 / 4, 256, 0, stream>>>(hA, score, perm, origA, origB, 0, hB, N2 / 8);
    k_map<<<Nq / 256, 256, 0, stream>>>(newpos, map, 0);
    k_readout_part<<<8 * 32, 256, 0, stream>>>(hB, part, NGq / 4, 32);
    k_readout_fin<<<4, 256, 0, stream>>>(part, z, NGq / 4, 32);

    // ---- Round 3: GCN W4(hB): xw -> hA[0:N2*64], out -> hA[N2*64:], pool -> hB
    k_xw<<<N2 * 64 / 256, 256, 0, stream>>>(hB, W4P, hA, N2);
    k_cntdis<<<N2 / 4, 256, 0, stream>>>(coff, csrc, map, origB, dis, N2 / 8);
    k_gcn_gather<<<N2 / 4, 256, 0, stream>>>(hA, coff, csrc, map, origB, dis,
                                             b4, wp4, hA + (size_t)N2 * 64, score, N2 / 8);
    k_topk<4><<<8, 1024, 0, stream>>>(score, newpos, perm);
    k_compact<<<N3 / 4, 256, 0, stream>>>(hA + (size_t)N2 * 64, score, perm,
                                          origB, origA, 0, hB, N3 / 8);
    k_map<<<Nq / 256, 256, 0, stream>>>(newpos, map, 0);
    k_readout_part<<<8 * 16, 256, 0, stream>>>(hB, part, NGq / 8, 16);
    k_readout_fin<<<4, 256, 0, stream>>>(part, z, NGq / 8, 16);

    // ---- Round 4: GCN W5(hB): xw -> hA[0:N3*64], out -> hA[N3*64:], pool -> hB
    k_xw<<<N3 * 64 / 256, 256, 0, stream>>>(hB, W5P, hA, N3);
    k_cntdis<<<N3 / 4, 256, 0, stream>>>(coff, csrc, map, origA, dis, N3 / 8);
    k_gcn_gather<<<N3 / 4, 256, 0, stream>>>(hA, coff, csrc, map, origA, dis,
                                             b5, wp5, hA + (size_t)N3 * 64, score, N3 / 8);
    k_topk<2><<<8, 1024, 0, stream>>>(score, newpos, perm);
    k_compact<<<N4 / 4, 256, 0, stream>>>(hA + (size_t)N3 * 64, score, perm,
                                          origA, origB, 0, hB, N4 / 8);
    k_readout_part<<<8 * 8, 256, 0, stream>>>(hB, part, NGq / 16, 8);
    k_readout_fin<<<4, 256, 0, stream>>>(part, z, NGq / 16, 8);

    // ---- MLP + softmax
    k_mlp<<<1, 256, 0, stream>>>(z, Wa, ba, Wb, bbv, Wc, bc, out);
}

// Round 10
// 687.281 us; speedup vs baseline: 1.1083x; 1.1083x over previous
//
#include <hip/hip_runtime.h>
#include <math.h>

constexpr int Bq  = 8;
constexpr int NGq = 16384;
constexpr int Nq  = Bq * NGq;       // 131072 nodes
constexpr int Eq  = Nq * 16;        // 2097152 edges
constexpr int Eg  = Eq / 8;         // 262144 edges per graph

// ---------------------------------------------------------------------------
// Transpose the four 64x64 weight matrices once per launch (R6 layout:
// WT[q*64+j] = W[j*64+q] — lane-consecutive scalar reads, proven 91 µs form)
// ---------------------------------------------------------------------------
__global__ void k_wt4(const float* __restrict__ A, const float* __restrict__ B,
                      const float* __restrict__ C, const float* __restrict__ D,
                      float* __restrict__ o) {
    const float* in = (blockIdx.x == 0) ? A : (blockIdx.x == 1) ? B
                     : (blockIdx.x == 2) ? C : D;
    float* out = o + (size_t)blockIdx.x * 4096;
    int t = threadIdx.x;
    for (int i = t; i < 4096; i += 256) {
        int r = i >> 6, c = i & 63;
        out[c * 64 + r] = in[r * 64 + c];
    }
}

// ---------------------------------------------------------------------------
// CSR build (by dst, storing src) — graph-per-XCD swizzled scatter
// ---------------------------------------------------------------------------
__global__ void k_cnt(const int* __restrict__ dst, int* __restrict__ cnt) {
    int blk = blockIdx.x;
    int g = blk & 7, c = blk >> 3;
    int e = g * Eg + c * 256 + threadIdx.x;
    atomicAdd(&cnt[dst[e]], 1);
}

__global__ void k_scan_a(const int* __restrict__ cnt, int* __restrict__ bsum) {
    __shared__ int s[4];
    int t = threadIdx.x;
    int v = cnt[blockIdx.x * 256 + t];
    for (int o = 32; o; o >>= 1) v += __shfl_xor(v, o);
    if ((t & 63) == 0) s[t >> 6] = v;
    __syncthreads();
    if (t == 0) bsum[blockIdx.x] = s[0] + s[1] + s[2] + s[3];
}

__global__ void k_scan_b(int* __restrict__ bsum) {
    __shared__ int s[512];
    int t = threadIdx.x;
    int own = bsum[t];
    s[t] = own;
    __syncthreads();
    for (int d = 1; d < 512; d <<= 1) {
        int v = (t >= d) ? s[t - d] : 0;
        __syncthreads();
        if (t >= d) s[t] += v;
        __syncthreads();
    }
    bsum[t] = s[t] - own;   // exclusive
}

__global__ void k_scan_c(const int* __restrict__ cnt, const int* __restrict__ bsum,
                         int* __restrict__ off, int* __restrict__ cursor) {
    __shared__ int s[4];
    int t = threadIdx.x, blk = blockIdx.x;
    int base = blk * 256;
    int v = cnt[base + t];
    int lane = t & 63, wv = t >> 6;
    int val = v;
    for (int o = 1; o < 64; o <<= 1) {
        int u = __shfl_up(val, o);
        if (lane >= o) val += u;
    }
    if (lane == 63) s[wv] = val;
    __syncthreads();
    int add = 0;
    for (int q = 0; q < wv; q++) add += s[q];
    int excl = val + add - v;
    int o0 = bsum[blk] + excl;
    off[base + t] = o0;
    cursor[base + t] = o0;
    if (blk == 0 && t == 0) off[Nq] = Eq;
}

__global__ void k_fill(const int* __restrict__ src, const int* __restrict__ dst,
                       int* __restrict__ cursor, int* __restrict__ csrc) {
    int blk = blockIdx.x;
    int g = blk & 7, c = blk >> 3;
    int e = g * Eg + c * 256 + threadIdx.x;
    int p = atomicAdd(&cursor[dst[e]], 1);
    if (p < Eq) csrc[p] = src[e];   // guard: keeps rocprof replay benign
}

// ---------------------------------------------------------------------------
// Round 1 SAGE (dim-2 input), fused conv + relu + topk-score. Wave per node.
// ---------------------------------------------------------------------------
__global__ void k_sage1(const float* __restrict__ x, const int* __restrict__ off,
                        const int* __restrict__ csrc,
                        const float* __restrict__ Wl, const float* __restrict__ bl,
                        const float* __restrict__ Wr, const float* __restrict__ wp,
                        float* __restrict__ out, float* __restrict__ score) {
    int blk = blockIdx.x;
    int g = blk & 7, i = blk >> 3;
    int wv = threadIdx.x >> 6, j = threadIdx.x & 63;
    int n = g * NGq + i * 4 + wv;
    int beg = off[n], end = off[n + 1];
    float2 xn = ((const float2*)x)[n];
    float s0 = 0.f, s1 = 0.f;
    for (int e = beg + j; e < end; e += 64) {
        float2 xv = ((const float2*)x)[csrc[e]];
        s0 += xv.x; s1 += xv.y;
    }
    for (int o = 32; o; o >>= 1) { s0 += __shfl_xor(s0, o); s1 += __shfl_xor(s1, o); }
    float c = fmaxf((float)(end - beg), 1.0f);
    float m0 = s0 / c, m1 = s1 / c;
    float v = Wl[2 * j] * m0 + Wl[2 * j + 1] * m1 + bl[j]
            + Wr[2 * j] * xn.x + Wr[2 * j + 1] * xn.y;
    v = fmaxf(v, 0.f);
    out[n * 64 + j] = v;
    float wvp = wp[j];
    float d = v * wvp, ww = wvp * wvp;
    for (int o = 32; o; o >>= 1) { d += __shfl_xor(d, o); ww += __shfl_xor(ww, o); }
    if (j == 0) score[n] = tanhf(d / sqrtf(ww));
}

// ---------------------------------------------------------------------------
// Per-graph top-k radix select — keys in registers (proven win, R8)
// ---------------------------------------------------------------------------
template<int M>
__global__ void k_topk(const float* __restrict__ score, int* __restrict__ newpos,
                       int* __restrict__ perm) {
    constexpr int n = M * 1024;
    constexpr int k = n / 2;
    __shared__ unsigned hist[256];
    __shared__ unsigned sh_pfx, sh_msk, sh_rem;
    __shared__ int sh_eqtot, sh_ctr;
    __shared__ int wtot[16];
    __shared__ int runTie, runGt;
    int t = threadIdx.x, b = blockIdx.x;
    int base = b * n;
    int lane = t & 63, wv = t >> 6;

    unsigned kr[M];
#pragma unroll
    for (int i = 0; i < M; i++) {
        unsigned u = __float_as_uint(score[base + t + (i << 10)]);
        kr[i] = u ^ ((u >> 31) ? 0xFFFFFFFFu : 0x80000000u);
    }
    if (t < 256) hist[t] = 0;
    if (t == 0) { sh_pfx = 0; sh_msk = 0; sh_rem = (unsigned)k;
                  sh_eqtot = 0; sh_ctr = 0; runTie = 0; runGt = 0; }
    __syncthreads();

    for (int shift = 24; shift >= 0; shift -= 8) {
        unsigned pfx = sh_pfx, msk = sh_msk;
#pragma unroll
        for (int i = 0; i < M; i++)
            if ((kr[i] & msk) == pfx) atomicAdd(&hist[(kr[i] >> shift) & 255], 1u);
        __syncthreads();
        if (t < 64) {
            unsigned rem = sh_rem;
            unsigned c0 = hist[255 - (t * 4 + 0)];
            unsigned c1 = hist[255 - (t * 4 + 1)];
            unsigned c2 = hist[255 - (t * 4 + 2)];
            unsigned c3 = hist[255 - (t * 4 + 3)];
            unsigned s = c0 + c1 + c2 + c3;
            unsigned sc = s;
            for (int o = 1; o < 64; o <<= 1) {
                unsigned u = __shfl_up(sc, o);
                if (t >= o) sc += u;
            }
            unsigned run = sc - s;
            unsigned cc[4] = {c0, c1, c2, c3};
#pragma unroll
            for (int q = 0; q < 4; q++) {
                unsigned incl = run + cc[q];
                if (run < rem && incl >= rem) {
                    int bb = 255 - (t * 4 + q);
                    sh_rem = rem - run;
                    sh_pfx = pfx | ((unsigned)bb << shift);
                    sh_msk = msk | (255u << shift);
                }
                run = incl;
            }
        }
        __syncthreads();
        if (t < 256) hist[t] = 0;
        __syncthreads();
    }
    unsigned K = sh_pfx;
    int T = (int)sh_rem;

    int le = 0;
#pragma unroll
    for (int i = 0; i < M; i++) le += (kr[i] == K) ? 1 : 0;
    for (int o = 32; o; o >>= 1) le += __shfl_xor(le, o);
    if (lane == 0) atomicAdd(&sh_eqtot, le);
    __syncthreads();

    if (sh_eqtot == T) {
        // fast path: every tie kept; order-free atomic compaction
#pragma unroll
        for (int i = 0; i < M; i++) {
            int cur = base + t + (i << 10);
            bool kept = kr[i] >= K;
            unsigned long long mk = __ballot(kept);
            int pos = 0;
            if (mk) {
                int fl = __ffsll(mk) - 1;
                int bp = 0;
                if (lane == fl) bp = atomicAdd(&sh_ctr, __popcll(mk));
                bp = __shfl(bp, fl);
                pos = bp + __popcll(mk & ((1ull << lane) - 1ull));
            }
            if (kept && pos < k) {
                newpos[cur] = b * k + pos;
                perm[b * k + pos] = cur;
            } else newpos[cur] = -1;
        }
    } else {
        // ordered fallback (rare)
        for (int i = 0; i < M; i++) {
            unsigned key = kr[i];
            int gt = key > K ? 1 : 0;
            int eq = key == K ? 1 : 0;
            int val = (eq << 16) | gt;
            for (int o = 1; o < 64; o <<= 1) {
                int v = __shfl_up(val, o);
                if (lane >= o) val += v;
            }
            if (lane == 63) wtot[wv] = val;
            __syncthreads();
            int add = 0;
            for (int q = 0; q < 16; q++) if (q < wv) add += wtot[q];
            val += add;
            int eqIncl = val >> 16, gtIncl = val & 0xffff;
            int eqExcl = eqIncl - eq, gtExcl = gtIncl - gt;
            int kept = gt | (eq & ((runTie + eqExcl) < T ? 1 : 0));
            int cur = base + t + (i << 10);
            if (kept) {
                int selEqBefore = runTie + eqExcl; if (selEqBefore > T) selEqBefore = T;
                int nl = runGt + gtExcl + selEqBefore;
                if (nl < k) {
                    newpos[cur] = b * k + nl;
                    perm[b * k + nl] = cur;
                } else newpos[cur] = -1;
            } else newpos[cur] = -1;
            __syncthreads();
            if (t == 1023) { runTie += eqIncl; runGt += gtIncl; }
            __syncthreads();
        }
    }
}

// gather kept rows gated by score; compose cur->orig id. Graph-swizzled.
__global__ void k_compact(const float* __restrict__ hin, const float* __restrict__ score,
                          const int* __restrict__ perm, const int* __restrict__ orig_in,
                          int* __restrict__ orig_out, int first,
                          float* __restrict__ hout, int k) {
    int blk = blockIdx.x;
    int g = blk & 7, i = blk >> 3;
    int wv = threadIdx.x >> 6, j = threadIdx.x & 63;
    int nn = g * k + i * 4 + wv;
    int old = perm[nn];
    hout[nn * 64 + j] = hin[old * 64 + j] * score[old];
    if (j == 0) orig_out[nn] = first ? old : orig_in[old];
}

__global__ void k_map(const int* __restrict__ newpos, int* __restrict__ map, int first) {
    int i = blockIdx.x * blockDim.x + threadIdx.x;
    if (i >= Nq) return;
    if (first) map[i] = newpos[i];
    else { int m = map[i]; map[i] = (m >= 0) ? newpos[m] : -1; }
}

// ---------------------------------------------------------------------------
// Readout [max | mean] — two-stage, graph-swizzled
// ---------------------------------------------------------------------------
__global__ void k_readout_part(const float* __restrict__ h, float* __restrict__ part,
                               int k, int G) {
    __shared__ float smx[256], ssm[256];
    int blk = blockIdx.x;
    int b = blk & 7, g = blk >> 3;
    int rows = k / G;
    int t = threadIdx.x, j = t & 63, q = t >> 6;
    const float* basep = h + ((size_t)b * k + (size_t)g * rows) * 64;
    float mx = -3.0e38f, sm = 0.f;
    for (int i = q; i < rows; i += 4) {
        float v = basep[i * 64 + j];
        mx = fmaxf(mx, v); sm += v;
    }
    smx[t] = mx; ssm[t] = sm;
    __syncthreads();
    if (q == 0) {
        for (int r = 1; r < 4; r++) { mx = fmaxf(mx, smx[j + 64 * r]); sm += ssm[j + 64 * r]; }
        part[(b * G + g) * 128 + j] = mx;
        part[(b * G + g) * 128 + 64 + j] = sm;
    }
}

__global__ void k_readout_fin(const float* __restrict__ part, float* __restrict__ z,
                              int k, int G) {
    int i = blockIdx.x * blockDim.x + threadIdx.x;
    if (i >= 8 * 128) return;
    int b = i >> 7, j = i & 127;
    if (j < 64) {
        float mx = -3.0e38f;
        for (int g = 0; g < G; g++) mx = fmaxf(mx, part[(b * G + g) * 128 + j]);
        z[b * 128 + j] += mx;
    } else {
        float sm = 0.f;
        for (int g = 0; g < G; g++) sm += part[(b * G + g) * 128 + j];
        z[b * 128 + j] += sm / (float)k;
    }
}

// ---------------------------------------------------------------------------
// SAGE round 2: R6-verbatim gather + scalar transposed-weight epilogue.
// (R8/R9 paired-float2 epilogue regressed: 32 VGPR register-starved
//  serialization, VALU 56%->34%. Keep the proven 91 µs form.)
// ---------------------------------------------------------------------------
__global__ void k_sage_gather(const float* __restrict__ h, const int* __restrict__ off,
                              const int* __restrict__ csrc, const int* __restrict__ map,
                              const int* __restrict__ orig,
                              const float* __restrict__ WlT, const float* __restrict__ bl,
                              const float* __restrict__ WrT, const float* __restrict__ wp,
                              float* __restrict__ out, float* __restrict__ score, int ng) {
    __shared__ float sh[4][128];
    int blk = blockIdx.x;
    int g = blk & 7, i = blk >> 3;
    int wv = threadIdx.x >> 6, j = threadIdx.x & 63;
    int n = g * ng + i * 4 + wv;
    int o = orig[n];
    int beg = off[o], end = off[o + 1];
    float own = h[n * 64 + j];           // hoisted: overlaps edge resolution
    float acc = 0.f; int cnt = 0;
    for (int base = beg; base < end; base += 64) {
        int d = end - base; if (d > 64) d = 64;
        int cs = (j < d) ? map[csrc[base + j]] : -1;
        cnt += __popcll(__ballot(cs >= 0));
        int e = 0;
        for (; e + 8 <= d; e += 8) {
            int c0 = __shfl(cs, e),     c1 = __shfl(cs, e + 1);
            int c2 = __shfl(cs, e + 2), c3 = __shfl(cs, e + 3);
            int c4 = __shfl(cs, e + 4), c5 = __shfl(cs, e + 5);
            int c6 = __shfl(cs, e + 6), c7 = __shfl(cs, e + 7);
            float v0 = (c0 >= 0) ? h[c0 * 64 + j] : 0.f;
            float v1 = (c1 >= 0) ? h[c1 * 64 + j] : 0.f;
            float v2 = (c2 >= 0) ? h[c2 * 64 + j] : 0.f;
            float v3 = (c3 >= 0) ? h[c3 * 64 + j] : 0.f;
            float v4 = (c4 >= 0) ? h[c4 * 64 + j] : 0.f;
            float v5 = (c5 >= 0) ? h[c5 * 64 + j] : 0.f;
            float v6 = (c6 >= 0) ? h[c6 * 64 + j] : 0.f;
            float v7 = (c7 >= 0) ? h[c7 * 64 + j] : 0.f;
            acc += ((v0 + v1) + (v2 + v3)) + ((v4 + v5) + (v6 + v7));
        }
        for (; e + 4 <= d; e += 4) {
            int c0 = __shfl(cs, e),     c1 = __shfl(cs, e + 1);
            int c2 = __shfl(cs, e + 2), c3 = __shfl(cs, e + 3);
            float v0 = (c0 >= 0) ? h[c0 * 64 + j] : 0.f;
            float v1 = (c1 >= 0) ? h[c1 * 64 + j] : 0.f;
            float v2 = (c2 >= 0) ? h[c2 * 64 + j] : 0.f;
            float v3 = (c3 >= 0) ? h[c3 * 64 + j] : 0.f;
            acc += (v0 + v1) + (v2 + v3);
        }
        for (; e < d; e++) {
            int c0 = __shfl(cs, e);
            if (c0 >= 0) acc += h[c0 * 64 + j];
        }
    }
    sh[wv][j] = acc / fmaxf((float)cnt, 1.0f);
    sh[wv][64 + j] = own;
    __syncthreads();
    const float* sm = sh[wv];
    float v = bl[j];
    // sm[q]/sm[64+q]: wave-uniform LDS broadcast; WT[q*64+j]: lane-consecutive
    for (int q = 0; q < 64; q++)
        v += sm[q] * WlT[q * 64 + j] + sm[64 + q] * WrT[q * 64 + j];
    v = fmaxf(v, 0.f);
    out[n * 64 + j] = v;
    float wvp = wp[j];
    float d = v * wvp, ww = wvp * wvp;
    for (int o2 = 32; o2; o2 >>= 1) { d += __shfl_xor(d, o2); ww += __shfl_xor(ww, o2); }
    if (j == 0) score[n] = tanhf(d / sqrtf(ww));
}

// ---------------------------------------------------------------------------
// GCN: xw = h @ W.T (scalar transposed weights, R6 form) ; cnt+dis ; gather
// ---------------------------------------------------------------------------
__global__ void k_xw(const float* __restrict__ h, const float* __restrict__ WT,
                     float* __restrict__ xw, int ntot) {
    int idx = blockIdx.x * blockDim.x + threadIdx.x;
    if (idx >= ntot * 64) return;
    int n = idx >> 6, j = idx & 63;
    const float* hr = &h[n * 64];    // wave-uniform (same address all lanes)
    float v = 0.f;
    for (int q = 0; q < 64; q++) v += hr[q] * WT[q * 64 + j];
    xw[idx] = v;
}

__global__ void k_cntdis(const int* __restrict__ off, const int* __restrict__ csrc,
                         const int* __restrict__ map, const int* __restrict__ orig,
                         float* __restrict__ dis, int ng) {
    int blk = blockIdx.x;
    int g = blk & 7, i = blk >> 3;
    int wv = threadIdx.x >> 6, j = threadIdx.x & 63;
    int n = g * ng + i * 4 + wv;
    int o = orig[n];
    int beg = off[o], end = off[o + 1];
    int c = 0;
    for (int base = beg; base < end; base += 64) {
        int d = end - base; if (d > 64) d = 64;
        int cs = (j < d) ? map[csrc[base + j]] : -1;
        c += __popcll(__ballot(cs >= 0));
    }
    if (j == 0) dis[n] = 1.0f / sqrtf(1.0f + (float)c);
}

__global__ void k_gcn_gather(const float* __restrict__ xw, const int* __restrict__ off,
                             const int* __restrict__ csrc, const int* __restrict__ map,
                             const int* __restrict__ orig, const float* __restrict__ dis,
                             const float* __restrict__ bb, const float* __restrict__ wp,
                             float* __restrict__ out, float* __restrict__ score, int ng) {
    int blk = blockIdx.x;
    int g = blk & 7, i = blk >> 3;
    int wv = threadIdx.x >> 6, j = threadIdx.x & 63;
    int n = g * ng + i * 4 + wv;
    int o = orig[n];
    int beg = off[o], end = off[o + 1];
    float dn = dis[n];
    float own = xw[n * 64 + j];
    float acc = 0.f;
    for (int base = beg; base < end; base += 64) {
        int d = end - base; if (d > 64) d = 64;
        int cs = -1; float dsv = 0.f;
        if (j < d) {
            int cc = map[csrc[base + j]];
            if (cc >= 0) { cs = cc; dsv = dis[cc]; }
        }
        int e = 0;
        for (; e + 8 <= d; e += 8) {
            int c0 = __shfl(cs, e),     c1 = __shfl(cs, e + 1);
            int c2 = __shfl(cs, e + 2), c3 = __shfl(cs, e + 3);
            int c4 = __shfl(cs, e + 4), c5 = __shfl(cs, e + 5);
            int c6 = __shfl(cs, e + 6), c7 = __shfl(cs, e + 7);
            float d0 = __shfl(dsv, e),     d1 = __shfl(dsv, e + 1);
            float d2 = __shfl(dsv, e + 2), d3 = __shfl(dsv, e + 3);
            float d4 = __shfl(dsv, e + 4), d5 = __shfl(dsv, e + 5);
            float d6 = __shfl(dsv, e + 6), d7 = __shfl(dsv, e + 7);
            float v0 = (c0 >= 0) ? xw[c0 * 64 + j] * d0 : 0.f;
            float v1 = (c1 >= 0) ? xw[c1 * 64 + j] * d1 : 0.f;
            float v2 = (c2 >= 0) ? xw[c2 * 64 + j] * d2 : 0.f;
            float v3 = (c3 >= 0) ? xw[c3 * 64 + j] * d3 : 0.f;
            float v4 = (c4 >= 0) ? xw[c4 * 64 + j] * d4 : 0.f;
            float v5 = (c5 >= 0) ? xw[c5 * 64 + j] * d5 : 0.f;
            float v6 = (c6 >= 0) ? xw[c6 * 64 + j] * d6 : 0.f;
            float v7 = (c7 >= 0) ? xw[c7 * 64 + j] * d7 : 0.f;
            acc += ((v0 + v1) + (v2 + v3)) + ((v4 + v5) + (v6 + v7));
        }
        for (; e + 4 <= d; e += 4) {
            int c0 = __shfl(cs, e),     c1 = __shfl(cs, e + 1);
            int c2 = __shfl(cs, e + 2), c3 = __shfl(cs, e + 3);
            float d0 = __shfl(dsv, e),     d1 = __shfl(dsv, e + 1);
            float d2 = __shfl(dsv, e + 2), d3 = __shfl(dsv, e + 3);
            float v0 = (c0 >= 0) ? xw[c0 * 64 + j] * d0 : 0.f;
            float v1 = (c1 >= 0) ? xw[c1 * 64 + j] * d1 : 0.f;
            float v2 = (c2 >= 0) ? xw[c2 * 64 + j] * d2 : 0.f;
            float v3 = (c3 >= 0) ? xw[c3 * 64 + j] * d3 : 0.f;
            acc += (v0 + v1) + (v2 + v3);
        }
        for (; e < d; e++) {
            int c0 = __shfl(cs, e);
            float d0 = __shfl(dsv, e);
            if (c0 >= 0) acc += xw[c0 * 64 + j] * d0;
        }
    }
    float v = acc * dn + own * dn * dn + bb[j];
    v = fmaxf(v, 0.f);
    out[n * 64 + j] = v;
    float wvp = wp[j];
    float d = v * wvp, ww = wvp * wvp;
    for (int o2 = 32; o2; o2 >>= 1) { d += __shfl_xor(d, o2); ww += __shfl_xor(ww, o2); }
    if (j == 0) score[n] = tanhf(d / sqrtf(ww));
}

// ---------------------------------------------------------------------------
// Final MLP + softmax: one block, all in LDS
// ---------------------------------------------------------------------------
__global__ void k_mlp(const float* __restrict__ z,
                      const float* __restrict__ Wa, const float* __restrict__ ba,
                      const float* __restrict__ Wb, const float* __restrict__ bb,
                      const float* __restrict__ Wc, const float* __restrict__ bc,
                      float* __restrict__ out) {
    __shared__ float sz[8 * 128];
    __shared__ float sa[8 * 128];
    __shared__ float sb[8 * 64];
    __shared__ float sc[8 * 256];
    int t = threadIdx.x;
    for (int i = t; i < 1024; i += 256) sz[i] = z[i];
    __syncthreads();
    for (int i = t; i < 1024; i += 256) {
        int b = i >> 7, o = i & 127;
        const float* wr = &Wa[o * 128];
        const float* zr = &sz[b * 128];
        float v = ba[o];
        for (int q = 0; q < 128; q++) v += zr[q] * wr[q];
        sa[i] = v > 0.f ? v : 0.f;
    }
    __syncthreads();
    for (int i = t; i < 512; i += 256) {
        int b = i >> 6, o = i & 63;
        const float* wr = &Wb[o * 128];
        const float* zr = &sa[b * 128];
        float v = bb[o];
        for (int q = 0; q < 128; q++) v += zr[q] * wr[q];
        sb[i] = v > 0.f ? v : 0.f;
    }
    __syncthreads();
    for (int i = t; i < 2048; i += 256) {
        int b = i >> 8, o = i & 255;
        const float* wr = &Wc[o * 64];
        const float* zr = &sb[b * 64];
        float v = bc[o];
        for (int q = 0; q < 64; q++) v += zr[q] * wr[q];
        sc[i] = v;
    }
    __syncthreads();
    int wv = t >> 6, ln = t & 63;
    for (int b = wv; b < 8; b += 4) {
        const float* row = &sc[b * 256];
        float m = -3.0e38f;
        for (int q = 0; q < 4; q++) m = fmaxf(m, row[ln + 64 * q]);
        for (int o = 32; o; o >>= 1) m = fmaxf(m, __shfl_xor(m, o));
        float s = 0.f;
        for (int q = 0; q < 4; q++) s += expf(row[ln + 64 * q] - m);
        for (int o = 32; o; o >>= 1) s += __shfl_xor(s, o);
        float inv = 1.f / s;
        for (int q = 0; q < 4; q++) out[b * 256 + ln + 64 * q] = expf(row[ln + 64 * q] - m) * inv;
    }
}

// ---------------------------------------------------------------------------
extern "C" void kernel_launch(void* const* d_in, const int* in_sizes, int n_in,
                              void* d_out, int out_size, void* d_ws, size_t ws_size,
                              hipStream_t stream) {
    const float* x   = (const float*)d_in[0];
    const int*   ei  = (const int*)d_in[1];
    const int* src = ei;
    const int* dst = ei + Eq;
    const float* Wl1 = (const float*)d_in[2];
    const float* bl1 = (const float*)d_in[3];
    const float* Wr1 = (const float*)d_in[4];
    const float* Wl2 = (const float*)d_in[5];
    const float* bl2 = (const float*)d_in[6];
    const float* Wr2 = (const float*)d_in[7];
    const float* W4  = (const float*)d_in[8];
    const float* b4  = (const float*)d_in[9];
    const float* W5  = (const float*)d_in[10];
    const float* b5  = (const float*)d_in[11];
    const float* wp1 = (const float*)d_in[12];
    const float* wp2 = (const float*)d_in[13];
    const float* wp4 = (const float*)d_in[14];
    const float* wp5 = (const float*)d_in[15];
    const float* Wa  = (const float*)d_in[16];
    const float* ba  = (const float*)d_in[17];
    const float* Wb  = (const float*)d_in[18];
    const float* bbv = (const float*)d_in[19];
    const float* Wc  = (const float*)d_in[20];
    const float* bc  = (const float*)d_in[21];
    float* out = (float*)d_out;

    const int N1 = Nq / 2, N2 = Nq / 4, N3 = Nq / 8, N4 = Nq / 16;

    // workspace layout (~64 MB)
    char* w = (char*)d_ws;
    float* hA    = (float*)w; w += (size_t)Nq * 64 * 4;        // 33.5 MB
    float* hB    = (float*)w; w += (size_t)N1 * 64 * 4;        // 16.8 MB
    int*   csrc  = (int*)w;   w += (size_t)Eq * 4;             //  8.4 MB
    int*   coff  = (int*)w;   w += (size_t)(Nq + 1) * 4;
    int*   cursor= (int*)w;   w += (size_t)Nq * 4;
    int*   cnt   = (int*)w;   w += (size_t)Nq * 4;
    float* dis   = (float*)w; w += (size_t)Nq * 4;
    float* score = (float*)w; w += (size_t)Nq * 4;
    int*   newpos= (int*)w;   w += (size_t)Nq * 4;
    int*   map   = (int*)w;   w += (size_t)Nq * 4;
    int*   perm  = (int*)w;   w += (size_t)Nq * 4;
    int*   origA = (int*)w;   w += (size_t)Nq * 4;
    int*   origB = (int*)w;   w += (size_t)Nq * 4;
    int*   bsum  = (int*)w;   w += 512 * 4;
    float* part  = (float*)w; w += (size_t)8 * 64 * 128 * 4;   // 256 KB
    float* z     = (float*)w; w += 1024 * 4;
    float* wT    = (float*)w; w += 4 * 4096 * 4;               // 64 KB
    float* WlT2 = wT, *WrT2 = wT + 4096, *W4T = wT + 8192, *W5T = wT + 12288;

    // ---- One-time: weight transposes + CSR build
    k_wt4<<<4, 256, 0, stream>>>(Wl2, Wr2, W4, W5, wT);
    hipMemsetAsync(cnt, 0, (size_t)Nq * 4, stream);
    hipMemsetAsync(z, 0, 1024 * 4, stream);
    k_cnt<<<Eq / 256, 256, 0, stream>>>(dst, cnt);
    k_scan_a<<<512, 256, 0, stream>>>(cnt, bsum);
    k_scan_b<<<1, 512, 0, stream>>>(bsum);
    k_scan_c<<<512, 256, 0, stream>>>(cnt, bsum, coff, cursor);
    k_fill<<<Eq / 256, 256, 0, stream>>>(src, dst, cursor, csrc);

    // ---- Round 1: SAGE1(x) -> hA [Nq x 64], pool -> hB [N1 x 64]
    k_sage1<<<Nq / 4, 256, 0, stream>>>(x, coff, csrc, Wl1, bl1, Wr1, wp1, hA, score);
    k_topk<16><<<8, 1024, 0, stream>>>(score, newpos, perm);
    k_compact<<<N1 / 4, 256, 0, stream>>>(hA, score, perm, nullptr, origA, 1, hB, N1 / 8);
    k_map<<<Nq / 256, 256, 0, stream>>>(newpos, map, 1);
    k_readout_part<<<8 * 64, 256, 0, stream>>>(hB, part, NGq / 2, 64);
    k_readout_fin<<<4, 256, 0, stream>>>(part, z, NGq / 2, 64);

    // ---- Round 2: SAGE2(hB) -> hA [N1 x 64], pool -> hB [N2 x 64]
    k_sage_gather<<<N1 / 4, 256, 0, stream>>>(hB, coff, csrc, map, origA,
                                              WlT2, bl2, WrT2, wp2, hA, score, N1 / 8);
    k_topk<8><<<8, 1024, 0, stream>>>(score, newpos, perm);
    k_compact<<<N2 / 4, 256, 0, stream>>>(hA, score, perm, origA, origB, 0, hB, N2 / 8);
    k_map<<<Nq / 256, 256, 0, stream>>>(newpos, map, 0);
    k_readout_part<<<8 * 32, 256, 0, stream>>>(hB, part, NGq / 4, 32);
    k_readout_fin<<<4, 256, 0, stream>>>(part, z, NGq / 4, 32);

    // ---- Round 3: GCN W4(hB): xw -> hA[0:N2*64], out -> hA[N2*64:], pool -> hB
    k_xw<<<N2 * 64 / 256, 256, 0, stream>>>(hB, W4T, hA, N2);
    k_cntdis<<<N2 / 4, 256, 0, stream>>>(coff, csrc, map, origB, dis, N2 / 8);
    k_gcn_gather<<<N2 / 4, 256, 0, stream>>>(hA, coff, csrc, map, origB, dis,
                                             b4, wp4, hA + (size_t)N2 * 64, score, N2 / 8);
    k_topk<4><<<8, 1024, 0, stream>>>(score, newpos, perm);
    k_compact<<<N3 / 4, 256, 0, stream>>>(hA + (size_t)N2 * 64, score, perm,
                                          origB, origA, 0, hB, N3 / 8);
    k_map<<<Nq / 256, 256, 0, stream>>>(newpos, map, 0);
    k_readout_part<<<8 * 16, 256, 0, stream>>>(hB, part, NGq / 8, 16);
    k_readout_fin<<<4, 256, 0, stream>>>(part, z, NGq / 8, 16);

    // ---- Round 4: GCN W5(hB): xw -> hA[0:N3*64], out -> hA[N3*64:], pool -> hB
    k_xw<<<N3 * 64 / 256, 256, 0, stream>>>(hB, W5T, hA, N3);
    k_cntdis<<<N3 / 4, 256, 0, stream>>>(coff, csrc, map, origA, dis, N3 / 8);
    k_gcn_gather<<<N3 / 4, 256, 0, stream>>>(hA, coff, csrc, map, origA, dis,
                                             b5, wp5, hA + (size_t)N3 * 64, score, N3 / 8);
    k_topk<2><<<8, 1024, 0, stream>>>(score, newpos, perm);
    k_compact<<<N4 / 4, 256, 0, stream>>>(hA + (size_t)N3 * 64, score, perm,
                                          origA, origB, 0, hB, N4 / 8);
    k_readout_part<<<8 * 8, 256, 0, stream>>>(hB, part, NGq / 16, 8);
    k_readout_fin<<<4, 256, 0, stream>>>(part, z, NGq / 16, 8);

    // ---- MLP + softmax
    k_mlp<<<1, 256, 0, stream>>>(z, Wa, ba, Wb, bbv, Wc, bc, out);
}

// Round 11
// 687.127 us; speedup vs baseline: 1.1086x; 1.0002x over previous
//
#include <hip/hip_runtime.h>
#include <math.h>

constexpr int Bq  = 8;
constexpr int NGq = 16384;
constexpr int Nq  = Bq * NGq;       // 131072 nodes
constexpr int Eq  = Nq * 16;        // 2097152 edges
constexpr int Eg  = Eq / 8;         // 262144 edges per graph

// ---------------------------------------------------------------------------
// Transpose the four 64x64 conv weight matrices (R6 layout, proven):
// WT[q*64+j] = W[j*64+q]
// ---------------------------------------------------------------------------
__global__ void k_wt4(const float* __restrict__ A, const float* __restrict__ B,
                      const float* __restrict__ C, const float* __restrict__ D,
                      float* __restrict__ o) {
    const float* in = (blockIdx.x == 0) ? A : (blockIdx.x == 1) ? B
                     : (blockIdx.x == 2) ? C : D;
    float* out = o + (size_t)blockIdx.x * 4096;
    int t = threadIdx.x;
    for (int i = t; i < 4096; i += 256) {
        int r = i >> 6, c = i & 63;
        out[c * 64 + r] = in[r * 64 + c];
    }
}

// Transpose the MLP weights: WaT[q*128+o] (128x128), WbT[q*64+o] (Wb is 64x128),
// WcT[q*256+o] (Wc is 256x64)
__global__ void k_wtmlp(const float* __restrict__ Wa, const float* __restrict__ Wb,
                        const float* __restrict__ Wc, float* __restrict__ o) {
    float* WaT = o;                  // 16384
    float* WbT = o + 16384;          //  8192
    float* WcT = o + 16384 + 8192;   // 16384
    int t = threadIdx.x;
    if (blockIdx.x == 0) {
        for (int i = t; i < 16384; i += 256) {
            int r = i >> 7, c = i & 127;
            WaT[c * 128 + r] = Wa[r * 128 + c];
        }
    } else if (blockIdx.x == 1) {
        for (int i = t; i < 8192; i += 256) {
            int r = i >> 7, c = i & 127;           // r<64 outputs, c<128 inputs
            WbT[c * 64 + r] = Wb[r * 128 + c];
        }
    } else {
        for (int i = t; i < 16384; i += 256) {
            int r = i >> 6, c = i & 63;            // r<256 outputs, c<64 inputs
            WcT[c * 256 + r] = Wc[r * 64 + c];
        }
    }
}

// ---------------------------------------------------------------------------
// CSR build (by dst, storing src) — graph-per-XCD swizzled scatter
// ---------------------------------------------------------------------------
__global__ void k_cnt(const int* __restrict__ dst, int* __restrict__ cnt) {
    int blk = blockIdx.x;
    int g = blk & 7, c = blk >> 3;
    int e = g * Eg + c * 256 + threadIdx.x;
    atomicAdd(&cnt[dst[e]], 1);
}

__global__ void k_scan_a(const int* __restrict__ cnt, int* __restrict__ bsum) {
    __shared__ int s[4];
    int t = threadIdx.x;
    int v = cnt[blockIdx.x * 256 + t];
    for (int o = 32; o; o >>= 1) v += __shfl_xor(v, o);
    if ((t & 63) == 0) s[t >> 6] = v;
    __syncthreads();
    if (t == 0) bsum[blockIdx.x] = s[0] + s[1] + s[2] + s[3];
}

__global__ void k_scan_b(int* __restrict__ bsum) {
    __shared__ int s[512];
    int t = threadIdx.x;
    int own = bsum[t];
    s[t] = own;
    __syncthreads();
    for (int d = 1; d < 512; d <<= 1) {
        int v = (t >= d) ? s[t - d] : 0;
        __syncthreads();
        if (t >= d) s[t] += v;
        __syncthreads();
    }
    bsum[t] = s[t] - own;   // exclusive
}

__global__ void k_scan_c(const int* __restrict__ cnt, const int* __restrict__ bsum,
                         int* __restrict__ off, int* __restrict__ cursor) {
    __shared__ int s[4];
    int t = threadIdx.x, blk = blockIdx.x;
    int base = blk * 256;
    int v = cnt[base + t];
    int lane = t & 63, wv = t >> 6;
    int val = v;
    for (int o = 1; o < 64; o <<= 1) {
        int u = __shfl_up(val, o);
        if (lane >= o) val += u;
    }
    if (lane == 63) s[wv] = val;
    __syncthreads();
    int add = 0;
    for (int q = 0; q < wv; q++) add += s[q];
    int excl = val + add - v;
    int o0 = bsum[blk] + excl;
    off[base + t] = o0;
    cursor[base + t] = o0;
    if (blk == 0 && t == 0) off[Nq] = Eq;
}

__global__ void k_fill(const int* __restrict__ src, const int* __restrict__ dst,
                       int* __restrict__ cursor, int* __restrict__ csrc) {
    int blk = blockIdx.x;
    int g = blk & 7, c = blk >> 3;
    int e = g * Eg + c * 256 + threadIdx.x;
    int p = atomicAdd(&cursor[dst[e]], 1);
    if (p < Eq) csrc[p] = src[e];   // guard: keeps rocprof replay benign
}

// ---------------------------------------------------------------------------
// Round 1 SAGE (dim-2 input), fused conv + relu + topk-score. Wave per node.
// ---------------------------------------------------------------------------
__global__ void k_sage1(const float* __restrict__ x, const int* __restrict__ off,
                        const int* __restrict__ csrc,
                        const float* __restrict__ Wl, const float* __restrict__ bl,
                        const float* __restrict__ Wr, const float* __restrict__ wp,
                        float* __restrict__ out, float* __restrict__ score) {
    int blk = blockIdx.x;
    int g = blk & 7, i = blk >> 3;
    int wv = threadIdx.x >> 6, j = threadIdx.x & 63;
    int n = g * NGq + i * 4 + wv;
    int beg = off[n], end = off[n + 1];
    float2 xn = ((const float2*)x)[n];
    float s0 = 0.f, s1 = 0.f;
    for (int e = beg + j; e < end; e += 64) {
        float2 xv = ((const float2*)x)[csrc[e]];
        s0 += xv.x; s1 += xv.y;
    }
    for (int o = 32; o; o >>= 1) { s0 += __shfl_xor(s0, o); s1 += __shfl_xor(s1, o); }
    float c = fmaxf((float)(end - beg), 1.0f);
    float m0 = s0 / c, m1 = s1 / c;
    float v = Wl[2 * j] * m0 + Wl[2 * j + 1] * m1 + bl[j]
            + Wr[2 * j] * xn.x + Wr[2 * j + 1] * xn.y;
    v = fmaxf(v, 0.f);
    out[n * 64 + j] = v;
    float wvp = wp[j];
    float d = v * wvp, ww = wvp * wvp;
    for (int o = 32; o; o >>= 1) { d += __shfl_xor(d, o); ww += __shfl_xor(ww, o); }
    if (j == 0) score[n] = tanhf(d / sqrtf(ww));
}

// ---------------------------------------------------------------------------
// Per-graph top-k radix select — keys in registers (proven win, R8)
// ---------------------------------------------------------------------------
template<int M>
__global__ void k_topk(const float* __restrict__ score, int* __restrict__ newpos,
                       int* __restrict__ perm) {
    constexpr int n = M * 1024;
    constexpr int k = n / 2;
    __shared__ unsigned hist[256];
    __shared__ unsigned sh_pfx, sh_msk, sh_rem;
    __shared__ int sh_eqtot, sh_ctr;
    __shared__ int wtot[16];
    __shared__ int runTie, runGt;
    int t = threadIdx.x, b = blockIdx.x;
    int base = b * n;
    int lane = t & 63, wv = t >> 6;

    unsigned kr[M];
#pragma unroll
    for (int i = 0; i < M; i++) {
        unsigned u = __float_as_uint(score[base + t + (i << 10)]);
        kr[i] = u ^ ((u >> 31) ? 0xFFFFFFFFu : 0x80000000u);
    }
    if (t < 256) hist[t] = 0;
    if (t == 0) { sh_pfx = 0; sh_msk = 0; sh_rem = (unsigned)k;
                  sh_eqtot = 0; sh_ctr = 0; runTie = 0; runGt = 0; }
    __syncthreads();

    for (int shift = 24; shift >= 0; shift -= 8) {
        unsigned pfx = sh_pfx, msk = sh_msk;
#pragma unroll
        for (int i = 0; i < M; i++)
            if ((kr[i] & msk) == pfx) atomicAdd(&hist[(kr[i] >> shift) & 255], 1u);
        __syncthreads();
        if (t < 64) {
            unsigned rem = sh_rem;
            unsigned c0 = hist[255 - (t * 4 + 0)];
            unsigned c1 = hist[255 - (t * 4 + 1)];
            unsigned c2 = hist[255 - (t * 4 + 2)];
            unsigned c3 = hist[255 - (t * 4 + 3)];
            unsigned s = c0 + c1 + c2 + c3;
            unsigned sc = s;
            for (int o = 1; o < 64; o <<= 1) {
                unsigned u = __shfl_up(sc, o);
                if (t >= o) sc += u;
            }
            unsigned run = sc - s;
            unsigned cc[4] = {c0, c1, c2, c3};
#pragma unroll
            for (int q = 0; q < 4; q++) {
                unsigned incl = run + cc[q];
                if (run < rem && incl >= rem) {
                    int bb = 255 - (t * 4 + q);
                    sh_rem = rem - run;
                    sh_pfx = pfx | ((unsigned)bb << shift);
                    sh_msk = msk | (255u << shift);
                }
                run = incl;
            }
        }
        __syncthreads();
        if (t < 256) hist[t] = 0;
        __syncthreads();
    }
    unsigned K = sh_pfx;
    int T = (int)sh_rem;

    int le = 0;
#pragma unroll
    for (int i = 0; i < M; i++) le += (kr[i] == K) ? 1 : 0;
    for (int o = 32; o; o >>= 1) le += __shfl_xor(le, o);
    if (lane == 0) atomicAdd(&sh_eqtot, le);
    __syncthreads();

    if (sh_eqtot == T) {
        // fast path: every tie kept; order-free atomic compaction
#pragma unroll
        for (int i = 0; i < M; i++) {
            int cur = base + t + (i << 10);
            bool kept = kr[i] >= K;
            unsigned long long mk = __ballot(kept);
            int pos = 0;
            if (mk) {
                int fl = __ffsll(mk) - 1;
                int bp = 0;
                if (lane == fl) bp = atomicAdd(&sh_ctr, __popcll(mk));
                bp = __shfl(bp, fl);
                pos = bp + __popcll(mk & ((1ull << lane) - 1ull));
            }
            if (kept && pos < k) {
                newpos[cur] = b * k + pos;
                perm[b * k + pos] = cur;
            } else newpos[cur] = -1;
        }
    } else {
        // ordered fallback (rare)
        for (int i = 0; i < M; i++) {
            unsigned key = kr[i];
            int gt = key > K ? 1 : 0;
            int eq = key == K ? 1 : 0;
            int val = (eq << 16) | gt;
            for (int o = 1; o < 64; o <<= 1) {
                int v = __shfl_up(val, o);
                if (lane >= o) val += v;
            }
            if (lane == 63) wtot[wv] = val;
            __syncthreads();
            int add = 0;
            for (int q = 0; q < 16; q++) if (q < wv) add += wtot[q];
            val += add;
            int eqIncl = val >> 16, gtIncl = val & 0xffff;
            int eqExcl = eqIncl - eq, gtExcl = gtIncl - gt;
            int kept = gt | (eq & ((runTie + eqExcl) < T ? 1 : 0));
            int cur = base + t + (i << 10);
            if (kept) {
                int selEqBefore = runTie + eqExcl; if (selEqBefore > T) selEqBefore = T;
                int nl = runGt + gtExcl + selEqBefore;
                if (nl < k) {
                    newpos[cur] = b * k + nl;
                    perm[b * k + nl] = cur;
                } else newpos[cur] = -1;
            } else newpos[cur] = -1;
            __syncthreads();
            if (t == 1023) { runTie += eqIncl; runGt += gtIncl; }
            __syncthreads();
        }
    }
}

// gather kept rows gated by score; compose cur->orig id. Graph-swizzled.
__global__ void k_compact(const float* __restrict__ hin, const float* __restrict__ score,
                          const int* __restrict__ perm, const int* __restrict__ orig_in,
                          int* __restrict__ orig_out, int first,
                          float* __restrict__ hout, int k) {
    int blk = blockIdx.x;
    int g = blk & 7, i = blk >> 3;
    int wv = threadIdx.x >> 6, j = threadIdx.x & 63;
    int nn = g * k + i * 4 + wv;
    int old = perm[nn];
    hout[nn * 64 + j] = hin[old * 64 + j] * score[old];
    if (j == 0) orig_out[nn] = first ? old : orig_in[old];
}

__global__ void k_map(const int* __restrict__ newpos, int* __restrict__ map, int first) {
    int i = blockIdx.x * blockDim.x + threadIdx.x;
    if (i >= Nq) return;
    if (first) map[i] = newpos[i];
    else { int m = map[i]; map[i] = (m >= 0) ? newpos[m] : -1; }
}

// ---------------------------------------------------------------------------
// Readout [max | mean] — two-stage, graph-swizzled
// ---------------------------------------------------------------------------
__global__ void k_readout_part(const float* __restrict__ h, float* __restrict__ part,
                               int k, int G) {
    __shared__ float smx[256], ssm[256];
    int blk = blockIdx.x;
    int b = blk & 7, g = blk >> 3;
    int rows = k / G;
    int t = threadIdx.x, j = t & 63, q = t >> 6;
    const float* basep = h + ((size_t)b * k + (size_t)g * rows) * 64;
    float mx = -3.0e38f, sm = 0.f;
    for (int i = q; i < rows; i += 4) {
        float v = basep[i * 64 + j];
        mx = fmaxf(mx, v); sm += v;
    }
    smx[t] = mx; ssm[t] = sm;
    __syncthreads();
    if (q == 0) {
        for (int r = 1; r < 4; r++) { mx = fmaxf(mx, smx[j + 64 * r]); sm += ssm[j + 64 * r]; }
        part[(b * G + g) * 128 + j] = mx;
        part[(b * G + g) * 128 + 64 + j] = sm;
    }
}

__global__ void k_readout_fin(const float* __restrict__ part, float* __restrict__ z,
                              int k, int G) {
    int i = blockIdx.x * blockDim.x + threadIdx.x;
    if (i >= 8 * 128) return;
    int b = i >> 7, j = i & 127;
    if (j < 64) {
        float mx = -3.0e38f;
        for (int g = 0; g < G; g++) mx = fmaxf(mx, part[(b * G + g) * 128 + j]);
        z[b * 128 + j] += mx;
    } else {
        float sm = 0.f;
        for (int g = 0; g < G; g++) sm += part[(b * G + g) * 128 + j];
        z[b * 128 + j] += sm / (float)k;
    }
}

// ---------------------------------------------------------------------------
// SAGE round 2: R6-verbatim gather + scalar transposed-weight epilogue.
// ---------------------------------------------------------------------------
__global__ void k_sage_gather(const float* __restrict__ h, const int* __restrict__ off,
                              const int* __restrict__ csrc, const int* __restrict__ map,
                              const int* __restrict__ orig,
                              const float* __restrict__ WlT, const float* __restrict__ bl,
                              const float* __restrict__ WrT, const float* __restrict__ wp,
                              float* __restrict__ out, float* __restrict__ score, int ng) {
    __shared__ float sh[4][128];
    int blk = blockIdx.x;
    int g = blk & 7, i = blk >> 3;
    int wv = threadIdx.x >> 6, j = threadIdx.x & 63;
    int n = g * ng + i * 4 + wv;
    int o = orig[n];
    int beg = off[o], end = off[o + 1];
    float own = h[n * 64 + j];           // hoisted: overlaps edge resolution
    float acc = 0.f; int cnt = 0;
    for (int base = beg; base < end; base += 64) {
        int d = end - base; if (d > 64) d = 64;
        int cs = (j < d) ? map[csrc[base + j]] : -1;
        cnt += __popcll(__ballot(cs >= 0));
        int e = 0;
        for (; e + 8 <= d; e += 8) {
            int c0 = __shfl(cs, e),     c1 = __shfl(cs, e + 1);
            int c2 = __shfl(cs, e + 2), c3 = __shfl(cs, e + 3);
            int c4 = __shfl(cs, e + 4), c5 = __shfl(cs, e + 5);
            int c6 = __shfl(cs, e + 6), c7 = __shfl(cs, e + 7);
            float v0 = (c0 >= 0) ? h[c0 * 64 + j] : 0.f;
            float v1 = (c1 >= 0) ? h[c1 * 64 + j] : 0.f;
            float v2 = (c2 >= 0) ? h[c2 * 64 + j] : 0.f;
            float v3 = (c3 >= 0) ? h[c3 * 64 + j] : 0.f;
            float v4 = (c4 >= 0) ? h[c4 * 64 + j] : 0.f;
            float v5 = (c5 >= 0) ? h[c5 * 64 + j] : 0.f;
            float v6 = (c6 >= 0) ? h[c6 * 64 + j] : 0.f;
            float v7 = (c7 >= 0) ? h[c7 * 64 + j] : 0.f;
            acc += ((v0 + v1) + (v2 + v3)) + ((v4 + v5) + (v6 + v7));
        }
        for (; e + 4 <= d; e += 4) {
            int c0 = __shfl(cs, e),     c1 = __shfl(cs, e + 1);
            int c2 = __shfl(cs, e + 2), c3 = __shfl(cs, e + 3);
            float v0 = (c0 >= 0) ? h[c0 * 64 + j] : 0.f;
            float v1 = (c1 >= 0) ? h[c1 * 64 + j] : 0.f;
            float v2 = (c2 >= 0) ? h[c2 * 64 + j] : 0.f;
            float v3 = (c3 >= 0) ? h[c3 * 64 + j] : 0.f;
            acc += (v0 + v1) + (v2 + v3);
        }
        for (; e < d; e++) {
            int c0 = __shfl(cs, e);
            if (c0 >= 0) acc += h[c0 * 64 + j];
        }
    }
    sh[wv][j] = acc / fmaxf((float)cnt, 1.0f);
    sh[wv][64 + j] = own;
    __syncthreads();
    const float* sm = sh[wv];
    float v = bl[j];
    for (int q = 0; q < 64; q++)
        v += sm[q] * WlT[q * 64 + j] + sm[64 + q] * WrT[q * 64 + j];
    v = fmaxf(v, 0.f);
    out[n * 64 + j] = v;
    float wvp = wp[j];
    float d = v * wvp, ww = wvp * wvp;
    for (int o2 = 32; o2; o2 >>= 1) { d += __shfl_xor(d, o2); ww += __shfl_xor(ww, o2); }
    if (j == 0) score[n] = tanhf(d / sqrtf(ww));
}

// ---------------------------------------------------------------------------
// GCN: xw = h @ W.T (scalar transposed weights) ; cnt+dis ; gather
// ---------------------------------------------------------------------------
__global__ void k_xw(const float* __restrict__ h, const float* __restrict__ WT,
                     float* __restrict__ xw, int ntot) {
    int idx = blockIdx.x * blockDim.x + threadIdx.x;
    if (idx >= ntot * 64) return;
    int n = idx >> 6, j = idx & 63;
    const float* hr = &h[n * 64];    // wave-uniform (same address all lanes)
    float v = 0.f;
    for (int q = 0; q < 64; q++) v += hr[q] * WT[q * 64 + j];
    xw[idx] = v;
}

__global__ void k_cntdis(const int* __restrict__ off, const int* __restrict__ csrc,
                         const int* __restrict__ map, const int* __restrict__ orig,
                         float* __restrict__ dis, int ng) {
    int blk = blockIdx.x;
    int g = blk & 7, i = blk >> 3;
    int wv = threadIdx.x >> 6, j = threadIdx.x & 63;
    int n = g * ng + i * 4 + wv;
    int o = orig[n];
    int beg = off[o], end = off[o + 1];
    int c = 0;
    for (int base = beg; base < end; base += 64) {
        int d = end - base; if (d > 64) d = 64;
        int cs = (j < d) ? map[csrc[base + j]] : -1;
        c += __popcll(__ballot(cs >= 0));
    }
    if (j == 0) dis[n] = 1.0f / sqrtf(1.0f + (float)c);
}

__global__ void k_gcn_gather(const float* __restrict__ xw, const int* __restrict__ off,
                             const int* __restrict__ csrc, const int* __restrict__ map,
                             const int* __restrict__ orig, const float* __restrict__ dis,
                             const float* __restrict__ bb, const float* __restrict__ wp,
                             float* __restrict__ out, float* __restrict__ score, int ng) {
    int blk = blockIdx.x;
    int g = blk & 7, i = blk >> 3;
    int wv = threadIdx.x >> 6, j = threadIdx.x & 63;
    int n = g * ng + i * 4 + wv;
    int o = orig[n];
    int beg = off[o], end = off[o + 1];
    float dn = dis[n];
    float own = xw[n * 64 + j];
    float acc = 0.f;
    for (int base = beg; base < end; base += 64) {
        int d = end - base; if (d > 64) d = 64;
        int cs = -1; float dsv = 0.f;
        if (j < d) {
            int cc = map[csrc[base + j]];
            if (cc >= 0) { cs = cc; dsv = dis[cc]; }
        }
        int e = 0;
        for (; e + 8 <= d; e += 8) {
            int c0 = __shfl(cs, e),     c1 = __shfl(cs, e + 1);
            int c2 = __shfl(cs, e + 2), c3 = __shfl(cs, e + 3);
            int c4 = __shfl(cs, e + 4), c5 = __shfl(cs, e + 5);
            int c6 = __shfl(cs, e + 6), c7 = __shfl(cs, e + 7);
            float d0 = __shfl(dsv, e),     d1 = __shfl(dsv, e + 1);
            float d2 = __shfl(dsv, e + 2), d3 = __shfl(dsv, e + 3);
            float d4 = __shfl(dsv, e + 4), d5 = __shfl(dsv, e + 5);
            float d6 = __shfl(dsv, e + 6), d7 = __shfl(dsv, e + 7);
            float v0 = (c0 >= 0) ? xw[c0 * 64 + j] * d0 : 0.f;
            float v1 = (c1 >= 0) ? xw[c1 * 64 + j] * d1 : 0.f;
            float v2 = (c2 >= 0) ? xw[c2 * 64 + j] * d2 : 0.f;
            float v3 = (c3 >= 0) ? xw[c3 * 64 + j] * d3 : 0.f;
            float v4 = (c4 >= 0) ? xw[c4 * 64 + j] * d4 : 0.f;
            float v5 = (c5 >= 0) ? xw[c5 * 64 + j] * d5 : 0.f;
            float v6 = (c6 >= 0) ? xw[c6 * 64 + j] * d6 : 0.f;
            float v7 = (c7 >= 0) ? xw[c7 * 64 + j] * d7 : 0.f;
            acc += ((v0 + v1) + (v2 + v3)) + ((v4 + v5) + (v6 + v7));
        }
        for (; e + 4 <= d; e += 4) {
            int c0 = __shfl(cs, e),     c1 = __shfl(cs, e + 1);
            int c2 = __shfl(cs, e + 2), c3 = __shfl(cs, e + 3);
            float d0 = __shfl(dsv, e),     d1 = __shfl(dsv, e + 1);
            float d2 = __shfl(dsv, e + 2), d3 = __shfl(dsv, e + 3);
            float v0 = (c0 >= 0) ? xw[c0 * 64 + j] * d0 : 0.f;
            float v1 = (c1 >= 0) ? xw[c1 * 64 + j] * d1 : 0.f;
            float v2 = (c2 >= 0) ? xw[c2 * 64 + j] * d2 : 0.f;
            float v3 = (c3 >= 0) ? xw[c3 * 64 + j] * d3 : 0.f;
            acc += (v0 + v1) + (v2 + v3);
        }
        for (; e < d; e++) {
            int c0 = __shfl(cs, e);
            float d0 = __shfl(dsv, e);
            if (c0 >= 0) acc += xw[c0 * 64 + j] * d0;
        }
    }
    float v = acc * dn + own * dn * dn + bb[j];
    v = fmaxf(v, 0.f);
    out[n * 64 + j] = v;
    float wvp = wp[j];
    float d = v * wvp, ww = wvp * wvp;
    for (int o2 = 32; o2; o2 >>= 1) { d += __shfl_xor(d, o2); ww += __shfl_xor(ww, o2); }
    if (j == 0) score[n] = tanhf(d / sqrtf(ww));
}

// ---------------------------------------------------------------------------
// Final MLP + softmax: 8 blocks (one per graph), transposed (coalesced) weights
// ---------------------------------------------------------------------------
__global__ void k_mlp(const float* __restrict__ z,
                      const float* __restrict__ WaT, const float* __restrict__ ba,
                      const float* __restrict__ WbT, const float* __restrict__ bb,
                      const float* __restrict__ WcT, const float* __restrict__ bc,
                      float* __restrict__ out) {
    __shared__ float sz[128];
    __shared__ float sa[128];
    __shared__ float sb2[64];
    __shared__ float sc[256];
    __shared__ float tmp[256];
    __shared__ float wred[4];
    int b = blockIdx.x, t = threadIdx.x;
    if (t < 128) sz[t] = z[b * 128 + t];
    __syncthreads();

    // layer A: 128 outputs, o = t&127; two half-ranges of q combined via LDS
    {
        int o = t & 127, half = t >> 7;
        float v = 0.f;
        int q0 = half * 64;
        for (int q = q0; q < q0 + 64; q++) v += sz[q] * WaT[q * 128 + o];
        tmp[t] = v;
        __syncthreads();
        if (t < 128) sa[t] = fmaxf(tmp[t] + tmp[t + 128] + ba[t], 0.f);
        __syncthreads();
    }
    // layer B: 64 outputs, o = t&63; four quarter-ranges of q
    {
        int o = t & 63, qr = t >> 6;
        float v = 0.f;
        int q0 = qr * 32;
        for (int q = q0; q < q0 + 32; q++) v += sa[q] * WbT[q * 64 + o];
        tmp[t] = v;
        __syncthreads();
        if (t < 64) sb2[t] = fmaxf(tmp[t] + tmp[t + 64] + tmp[t + 128] + tmp[t + 192] + bb[t], 0.f);
        __syncthreads();
    }
    // layer C: 256 outputs, one per thread
    {
        float v = bc[t];
        for (int q = 0; q < 64; q++) v += sb2[q] * WcT[q * 256 + t];
        sc[t] = v;
    }
    __syncthreads();
    // softmax over 256
    float m = sc[t];
    for (int o2 = 32; o2; o2 >>= 1) m = fmaxf(m, __shfl_xor(m, o2));
    if ((t & 63) == 0) wred[t >> 6] = m;
    __syncthreads();
    m = fmaxf(fmaxf(wred[0], wred[1]), fmaxf(wred[2], wred[3]));
    __syncthreads();
    float e = expf(sc[t] - m);
    float s = e;
    for (int o2 = 32; o2; o2 >>= 1) s += __shfl_xor(s, o2);
    if ((t & 63) == 0) wred[t >> 6] = s;
    __syncthreads();
    s = wred[0] + wred[1] + wred[2] + wred[3];
    out[b * 256 + t] = e / s;
}

// ---------------------------------------------------------------------------
extern "C" void kernel_launch(void* const* d_in, const int* in_sizes, int n_in,
                              void* d_out, int out_size, void* d_ws, size_t ws_size,
                              hipStream_t stream) {
    const float* x   = (const float*)d_in[0];
    const int*   ei  = (const int*)d_in[1];
    const int* src = ei;
    const int* dst = ei + Eq;
    const float* Wl1 = (const float*)d_in[2];
    const float* bl1 = (const float*)d_in[3];
    const float* Wr1 = (const float*)d_in[4];
    const float* Wl2 = (const float*)d_in[5];
    const float* bl2 = (const float*)d_in[6];
    const float* Wr2 = (const float*)d_in[7];
    const float* W4  = (const float*)d_in[8];
    const float* b4  = (const float*)d_in[9];
    const float* W5  = (const float*)d_in[10];
    const float* b5  = (const float*)d_in[11];
    const float* wp1 = (const float*)d_in[12];
    const float* wp2 = (const float*)d_in[13];
    const float* wp4 = (const float*)d_in[14];
    const float* wp5 = (const float*)d_in[15];
    const float* Wa  = (const float*)d_in[16];
    const float* ba  = (const float*)d_in[17];
    const float* Wb  = (const float*)d_in[18];
    const float* bbv = (const float*)d_in[19];
    const float* Wc  = (const float*)d_in[20];
    const float* bc  = (const float*)d_in[21];
    float* out = (float*)d_out;

    const int N1 = Nq / 2, N2 = Nq / 4, N3 = Nq / 8, N4 = Nq / 16;

    // workspace layout (~64 MB)
    char* w = (char*)d_ws;
    float* hA    = (float*)w; w += (size_t)Nq * 64 * 4;        // 33.5 MB
    float* hB    = (float*)w; w += (size_t)N1 * 64 * 4;        // 16.8 MB
    int*   csrc  = (int*)w;   w += (size_t)Eq * 4;             //  8.4 MB
    int*   coff  = (int*)w;   w += (size_t)(Nq + 1) * 4;
    int*   cursor= (int*)w;   w += (size_t)Nq * 4;
    int*   cnt   = (int*)w;   w += (size_t)Nq * 4;
    float* dis   = (float*)w; w += (size_t)Nq * 4;
    float* score = (float*)w; w += (size_t)Nq * 4;
    int*   newpos= (int*)w;   w += (size_t)Nq * 4;
    int*   map   = (int*)w;   w += (size_t)Nq * 4;
    int*   perm  = (int*)w;   w += (size_t)Nq * 4;
    int*   origA = (int*)w;   w += (size_t)Nq * 4;
    int*   origB = (int*)w;   w += (size_t)Nq * 4;
    int*   bsum  = (int*)w;   w += 512 * 4;
    float* part  = (float*)w; w += (size_t)8 * 64 * 128 * 4;   // 256 KB
    float* z     = (float*)w; w += 1024 * 4;
    float* wT    = (float*)w; w += 4 * 4096 * 4;               // 64 KB
    float* wMT   = (float*)w; w += (16384 + 8192 + 16384) * 4; // 160 KB
    float* WlT2 = wT, *WrT2 = wT + 4096, *W4T = wT + 8192, *W5T = wT + 12288;
    float* WaT = wMT, *WbT = wMT + 16384, *WcT = wMT + 16384 + 8192;

    // ---- One-time: weight transposes + CSR build
    k_wt4<<<4, 256, 0, stream>>>(Wl2, Wr2, W4, W5, wT);
    k_wtmlp<<<3, 256, 0, stream>>>(Wa, Wb, Wc, wMT);
    hipMemsetAsync(cnt, 0, (size_t)Nq * 4, stream);
    hipMemsetAsync(z, 0, 1024 * 4, stream);
    k_cnt<<<Eq / 256, 256, 0, stream>>>(dst, cnt);
    k_scan_a<<<512, 256, 0, stream>>>(cnt, bsum);
    k_scan_b<<<1, 512, 0, stream>>>(bsum);
    k_scan_c<<<512, 256, 0, stream>>>(cnt, bsum, coff, cursor);
    k_fill<<<Eq / 256, 256, 0, stream>>>(src, dst, cursor, csrc);

    // ---- Round 1: SAGE1(x) -> hA [Nq x 64], pool -> hB [N1 x 64]
    k_sage1<<<Nq / 4, 256, 0, stream>>>(x, coff, csrc, Wl1, bl1, Wr1, wp1, hA, score);
    k_topk<16><<<8, 1024, 0, stream>>>(score, newpos, perm);
    k_compact<<<N1 / 4, 256, 0, stream>>>(hA, score, perm, nullptr, origA, 1, hB, N1 / 8);
    k_map<<<Nq / 256, 256, 0, stream>>>(newpos, map, 1);
    k_readout_part<<<8 * 64, 256, 0, stream>>>(hB, part, NGq / 2, 64);
    k_readout_fin<<<4, 256, 0, stream>>>(part, z, NGq / 2, 64);

    // ---- Round 2: SAGE2(hB) -> hA [N1 x 64], pool -> hB [N2 x 64]
    k_sage_gather<<<N1 / 4, 256, 0, stream>>>(hB, coff, csrc, map, origA,
                                              WlT2, bl2, WrT2, wp2, hA, score, N1 / 8);
    k_topk<8><<<8, 1024, 0, stream>>>(score, newpos, perm);
    k_compact<<<N2 / 4, 256, 0, stream>>>(hA, score, perm, origA, origB, 0, hB, N2 / 8);
    k_map<<<Nq / 256, 256, 0, stream>>>(newpos, map, 0);
    k_readout_part<<<8 * 32, 256, 0, stream>>>(hB, part, NGq / 4, 32);
    k_readout_fin<<<4, 256, 0, stream>>>(part, z, NGq / 4, 32);

    // ---- Round 3: GCN W4(hB): xw -> hA[0:N2*64], out -> hA[N2*64:], pool -> hB
    k_xw<<<N2 * 64 / 256, 256, 0, stream>>>(hB, W4T, hA, N2);
    k_cntdis<<<N2 / 4, 256, 0, stream>>>(coff, csrc, map, origB, dis, N2 / 8);
    k_gcn_gather<<<N2 / 4, 256, 0, stream>>>(hA, coff, csrc, map, origB, dis,
                                             b4, wp4, hA + (size_t)N2 * 64, score, N2 / 8);
    k_topk<4><<<8, 1024, 0, stream>>>(score, newpos, perm);
    k_compact<<<N3 / 4, 256, 0, stream>>>(hA + (size_t)N2 * 64, score, perm,
                                          origB, origA, 0, hB, N3 / 8);
    k_map<<<Nq / 256, 256, 0, stream>>>(newpos, map, 0);
    k_readout_part<<<8 * 16, 256, 0, stream>>>(hB, part, NGq / 8, 16);
    k_readout_fin<<<4, 256, 0, stream>>>(part, z, NGq / 8, 16);

    // ---- Round 4: GCN W5(hB): xw -> hA[0:N3*64], out -> hA[N3*64:], pool -> hB
    k_xw<<<N3 * 64 / 256, 256, 0, stream>>>(hB, W5T, hA, N3);
    k_cntdis<<<N3 / 4, 256, 0, stream>>>(coff, csrc, map, origA, dis, N3 / 8);
    k_gcn_gather<<<N3 / 4, 256, 0, stream>>>(hA, coff, csrc, map, origA, dis,
                                             b5, wp5, hA + (size_t)N3 * 64, score, N3 / 8);
    k_topk<2><<<8, 1024, 0, stream>>>(score, newpos, perm);
    k_compact<<<N4 / 4, 256, 0, stream>>>(hA + (size_t)N3 * 64, score, perm,
                                          origA, origB, 0, hB, N4 / 8);
    k_readout_part<<<8 * 8, 256, 0, stream>>>(hB, part, NGq / 16, 8);
    k_readout_fin<<<4, 256, 0, stream>>>(part, z, NGq / 16, 8);

    // ---- MLP + softmax (8 blocks, coalesced weights)
    k_mlp<<<8, 256, 0, stream>>>(z, WaT, ba, WbT, bbv, WcT, bc, out);
}

// Round 12
// 678.250 us; speedup vs baseline: 1.1231x; 1.0131x over previous
//
#include <hip/hip_runtime.h>
#include <math.h>

constexpr int Bq  = 8;
constexpr int NGq = 16384;
constexpr int Nq  = Bq * NGq;       // 131072 nodes
constexpr int Eq  = Nq * 16;        // 2097152 edges
constexpr int Eg  = Eq / 8;         // 262144 edges per graph

// ---------------------------------------------------------------------------
// Transpose the four 64x64 conv weight matrices (proven layout):
// WT[q*64+j] = W[j*64+q]
// ---------------------------------------------------------------------------
__global__ void k_wt4(const float* __restrict__ A, const float* __restrict__ B,
                      const float* __restrict__ C, const float* __restrict__ D,
                      float* __restrict__ o) {
    const float* in = (blockIdx.x == 0) ? A : (blockIdx.x == 1) ? B
                     : (blockIdx.x == 2) ? C : D;
    float* out = o + (size_t)blockIdx.x * 4096;
    int t = threadIdx.x;
    for (int i = t; i < 4096; i += 256) {
        int r = i >> 6, c = i & 63;
        out[c * 64 + r] = in[r * 64 + c];
    }
}

// Transposed MLP weights: WaT[q*128+o], WbT[q*64+o], WcT[q*256+o]
__global__ void k_wtmlp(const float* __restrict__ Wa, const float* __restrict__ Wb,
                        const float* __restrict__ Wc, float* __restrict__ o) {
    float* WaT = o;
    float* WbT = o + 16384;
    float* WcT = o + 16384 + 8192;
    int t = threadIdx.x;
    if (blockIdx.x == 0) {
        for (int i = t; i < 16384; i += 256) {
            int r = i >> 7, c = i & 127;
            WaT[c * 128 + r] = Wa[r * 128 + c];
        }
    } else if (blockIdx.x == 1) {
        for (int i = t; i < 8192; i += 256) {
            int r = i >> 7, c = i & 127;
            WbT[c * 64 + r] = Wb[r * 128 + c];
        }
    } else {
        for (int i = t; i < 16384; i += 256) {
            int r = i >> 6, c = i & 63;
            WcT[c * 256 + r] = Wc[r * 64 + c];
        }
    }
}

// ---------------------------------------------------------------------------
// CSR build (by dst, storing src) — graph-per-XCD swizzled scatter
// ---------------------------------------------------------------------------
__global__ void k_cnt(const int* __restrict__ dst, int* __restrict__ cnt) {
    int blk = blockIdx.x;
    int g = blk & 7, c = blk >> 3;
    int e = g * Eg + c * 256 + threadIdx.x;
    atomicAdd(&cnt[dst[e]], 1);
}

__global__ void k_scan_a(const int* __restrict__ cnt, int* __restrict__ bsum) {
    __shared__ int s[4];
    int t = threadIdx.x;
    int v = cnt[blockIdx.x * 256 + t];
    for (int o = 32; o; o >>= 1) v += __shfl_xor(v, o);
    if ((t & 63) == 0) s[t >> 6] = v;
    __syncthreads();
    if (t == 0) bsum[blockIdx.x] = s[0] + s[1] + s[2] + s[3];
}

__global__ void k_scan_b(int* __restrict__ bsum) {
    __shared__ int s[512];
    int t = threadIdx.x;
    int own = bsum[t];
    s[t] = own;
    __syncthreads();
    for (int d = 1; d < 512; d <<= 1) {
        int v = (t >= d) ? s[t - d] : 0;
        __syncthreads();
        if (t >= d) s[t] += v;
        __syncthreads();
    }
    bsum[t] = s[t] - own;   // exclusive
}

__global__ void k_scan_c(const int* __restrict__ cnt, const int* __restrict__ bsum,
                         int* __restrict__ off, int* __restrict__ cursor) {
    __shared__ int s[4];
    int t = threadIdx.x, blk = blockIdx.x;
    int base = blk * 256;
    int v = cnt[base + t];
    int lane = t & 63, wv = t >> 6;
    int val = v;
    for (int o = 1; o < 64; o <<= 1) {
        int u = __shfl_up(val, o);
        if (lane >= o) val += u;
    }
    if (lane == 63) s[wv] = val;
    __syncthreads();
    int add = 0;
    for (int q = 0; q < wv; q++) add += s[q];
    int excl = val + add - v;
    int o0 = bsum[blk] + excl;
    off[base + t] = o0;
    cursor[base + t] = o0;
    if (blk == 0 && t == 0) off[Nq] = Eq;
}

__global__ void k_fill(const int* __restrict__ src, const int* __restrict__ dst,
                       int* __restrict__ cursor, int* __restrict__ csrc) {
    int blk = blockIdx.x;
    int g = blk & 7, c = blk >> 3;
    int e = g * Eg + c * 256 + threadIdx.x;
    int p = atomicAdd(&cursor[dst[e]], 1);
    if (p < Eq) csrc[p] = src[e];   // guard: keeps rocprof replay benign
}

// ---------------------------------------------------------------------------
// Round 1 SAGE (dim-2 input), fused conv + relu + topk-score. Wave per node.
// ---------------------------------------------------------------------------
__global__ void k_sage1(const float* __restrict__ x, const int* __restrict__ off,
                        const int* __restrict__ csrc,
                        const float* __restrict__ Wl, const float* __restrict__ bl,
                        const float* __restrict__ Wr, const float* __restrict__ wp,
                        float* __restrict__ out, float* __restrict__ score) {
    int blk = blockIdx.x;
    int g = blk & 7, i = blk >> 3;
    int wv = threadIdx.x >> 6, j = threadIdx.x & 63;
    int n = g * NGq + i * 4 + wv;
    int beg = off[n], end = off[n + 1];
    float2 xn = ((const float2*)x)[n];
    float s0 = 0.f, s1 = 0.f;
    for (int e = beg + j; e < end; e += 64) {
        float2 xv = ((const float2*)x)[csrc[e]];
        s0 += xv.x; s1 += xv.y;
    }
    for (int o = 32; o; o >>= 1) { s0 += __shfl_xor(s0, o); s1 += __shfl_xor(s1, o); }
    float c = fmaxf((float)(end - beg), 1.0f);
    float m0 = s0 / c, m1 = s1 / c;
    float v = Wl[2 * j] * m0 + Wl[2 * j + 1] * m1 + bl[j]
            + Wr[2 * j] * xn.x + Wr[2 * j + 1] * xn.y;
    v = fmaxf(v, 0.f);
    out[n * 64 + j] = v;
    float wvp = wp[j];
    float d = v * wvp, ww = wvp * wvp;
    for (int o = 32; o; o >>= 1) { d += __shfl_xor(d, o); ww += __shfl_xor(ww, o); }
    if (j == 0) score[n] = tanhf(d / sqrtf(ww));
}

// ---------------------------------------------------------------------------
// Per-graph top-k radix select (keys in registers) + fused map update.
// mode: 0 = no map update, 1 = map[i]=newpos[i], 2 = compose map through newpos
// Block b owns graph b, so its map slice depends only on its own newpos writes
// (visible after __syncthreads, which drains vmem on CDNA).
// ---------------------------------------------------------------------------
template<int M>
__global__ void k_topk(const float* __restrict__ score, int* __restrict__ newpos,
                       int* __restrict__ perm, int* __restrict__ map, int mode) {
    constexpr int n = M * 1024;
    constexpr int k = n / 2;
    __shared__ unsigned hist[256];
    __shared__ unsigned sh_pfx, sh_msk, sh_rem;
    __shared__ int sh_eqtot, sh_ctr;
    __shared__ int wtot[16];
    __shared__ int runTie, runGt;
    int t = threadIdx.x, b = blockIdx.x;
    int base = b * n;
    int lane = t & 63, wv = t >> 6;

    unsigned kr[M];
#pragma unroll
    for (int i = 0; i < M; i++) {
        unsigned u = __float_as_uint(score[base + t + (i << 10)]);
        kr[i] = u ^ ((u >> 31) ? 0xFFFFFFFFu : 0x80000000u);
    }
    if (t < 256) hist[t] = 0;
    if (t == 0) { sh_pfx = 0; sh_msk = 0; sh_rem = (unsigned)k;
                  sh_eqtot = 0; sh_ctr = 0; runTie = 0; runGt = 0; }
    __syncthreads();

    for (int shift = 24; shift >= 0; shift -= 8) {
        unsigned pfx = sh_pfx, msk = sh_msk;
#pragma unroll
        for (int i = 0; i < M; i++)
            if ((kr[i] & msk) == pfx) atomicAdd(&hist[(kr[i] >> shift) & 255], 1u);
        __syncthreads();
        if (t < 64) {
            unsigned rem = sh_rem;
            unsigned c0 = hist[255 - (t * 4 + 0)];
            unsigned c1 = hist[255 - (t * 4 + 1)];
            unsigned c2 = hist[255 - (t * 4 + 2)];
            unsigned c3 = hist[255 - (t * 4 + 3)];
            unsigned s = c0 + c1 + c2 + c3;
            unsigned sc = s;
            for (int o = 1; o < 64; o <<= 1) {
                unsigned u = __shfl_up(sc, o);
                if (t >= o) sc += u;
            }
            unsigned run = sc - s;
            unsigned cc[4] = {c0, c1, c2, c3};
#pragma unroll
            for (int q = 0; q < 4; q++) {
                unsigned incl = run + cc[q];
                if (run < rem && incl >= rem) {
                    int bb = 255 - (t * 4 + q);
                    sh_rem = rem - run;
                    sh_pfx = pfx | ((unsigned)bb << shift);
                    sh_msk = msk | (255u << shift);
                }
                run = incl;
            }
        }
        __syncthreads();
        if (t < 256) hist[t] = 0;
        __syncthreads();
    }
    unsigned K = sh_pfx;
    int T = (int)sh_rem;

    int le = 0;
#pragma unroll
    for (int i = 0; i < M; i++) le += (kr[i] == K) ? 1 : 0;
    for (int o = 32; o; o >>= 1) le += __shfl_xor(le, o);
    if (lane == 0) atomicAdd(&sh_eqtot, le);
    __syncthreads();

    if (sh_eqtot == T) {
        // fast path: every tie kept; order-free atomic compaction
#pragma unroll
        for (int i = 0; i < M; i++) {
            int cur = base + t + (i << 10);
            bool kept = kr[i] >= K;
            unsigned long long mk = __ballot(kept);
            int pos = 0;
            if (mk) {
                int fl = __ffsll(mk) - 1;
                int bp = 0;
                if (lane == fl) bp = atomicAdd(&sh_ctr, __popcll(mk));
                bp = __shfl(bp, fl);
                pos = bp + __popcll(mk & ((1ull << lane) - 1ull));
            }
            if (kept && pos < k) {
                newpos[cur] = b * k + pos;
                perm[b * k + pos] = cur;
            } else newpos[cur] = -1;
        }
    } else {
        // ordered fallback (rare)
        for (int i = 0; i < M; i++) {
            unsigned key = kr[i];
            int gt = key > K ? 1 : 0;
            int eq = key == K ? 1 : 0;
            int val = (eq << 16) | gt;
            for (int o = 1; o < 64; o <<= 1) {
                int v = __shfl_up(val, o);
                if (lane >= o) val += v;
            }
            if (lane == 63) wtot[wv] = val;
            __syncthreads();
            int add = 0;
            for (int q = 0; q < 16; q++) if (q < wv) add += wtot[q];
            val += add;
            int eqIncl = val >> 16, gtIncl = val & 0xffff;
            int eqExcl = eqIncl - eq, gtExcl = gtIncl - gt;
            int kept = gt | (eq & ((runTie + eqExcl) < T ? 1 : 0));
            int cur = base + t + (i << 10);
            if (kept) {
                int selEqBefore = runTie + eqExcl; if (selEqBefore > T) selEqBefore = T;
                int nl = runGt + gtExcl + selEqBefore;
                if (nl < k) {
                    newpos[cur] = b * k + nl;
                    perm[b * k + nl] = cur;
                } else newpos[cur] = -1;
            } else newpos[cur] = -1;
            __syncthreads();
            if (t == 1023) { runTie += eqIncl; runGt += gtIncl; }
            __syncthreads();
        }
    }

    // fused map update: graph b's original-node slice [b*NGq, (b+1)*NGq)
    if (mode) {
        __syncthreads();   // drain newpos writes (vmcnt 0) before reading them
        int gbase = b * NGq;
        for (int i2 = t; i2 < NGq; i2 += 1024) {
            int gi = gbase + i2;
            if (mode == 1) map[gi] = newpos[gi];
            else { int m = map[gi]; map[gi] = (m >= 0) ? newpos[m] : -1; }
        }
    }
}

// gather kept rows gated by score; compose cur->orig id. Graph-swizzled.
__global__ void k_compact(const float* __restrict__ hin, const float* __restrict__ score,
                          const int* __restrict__ perm, const int* __restrict__ orig_in,
                          int* __restrict__ orig_out, int first,
                          float* __restrict__ hout, int k) {
    int blk = blockIdx.x;
    int g = blk & 7, i = blk >> 3;
    int wv = threadIdx.x >> 6, j = threadIdx.x & 63;
    int nn = g * k + i * 4 + wv;
    int old = perm[nn];
    hout[nn * 64 + j] = hin[old * 64 + j] * score[old];
    if (j == 0) orig_out[nn] = first ? old : orig_in[old];
}

// ---------------------------------------------------------------------------
// Readout [max | mean] — two-stage, graph-swizzled
// ---------------------------------------------------------------------------
__global__ void k_readout_part(const float* __restrict__ h, float* __restrict__ part,
                               int k, int G) {
    __shared__ float smx[256], ssm[256];
    int blk = blockIdx.x;
    int b = blk & 7, g = blk >> 3;
    int rows = k / G;
    int t = threadIdx.x, j = t & 63, q = t >> 6;
    const float* basep = h + ((size_t)b * k + (size_t)g * rows) * 64;
    float mx = -3.0e38f, sm = 0.f;
    for (int i = q; i < rows; i += 4) {
        float v = basep[i * 64 + j];
        mx = fmaxf(mx, v); sm += v;
    }
    smx[t] = mx; ssm[t] = sm;
    __syncthreads();
    if (q == 0) {
        for (int r = 1; r < 4; r++) { mx = fmaxf(mx, smx[j + 64 * r]); sm += ssm[j + 64 * r]; }
        part[(b * G + g) * 128 + j] = mx;
        part[(b * G + g) * 128 + 64 + j] = sm;
    }
}

__global__ void k_readout_fin(const float* __restrict__ part, float* __restrict__ z,
                              int k, int G) {
    int i = blockIdx.x * blockDim.x + threadIdx.x;
    if (i >= 8 * 128) return;
    int b = i >> 7, j = i & 127;
    if (j < 64) {
        float mx = -3.0e38f;
        for (int g = 0; g < G; g++) mx = fmaxf(mx, part[(b * G + g) * 128 + j]);
        z[b * 128 + j] += mx;
    } else {
        float sm = 0.f;
        for (int g = 0; g < G; g++) sm += part[(b * G + g) * 128 + j];
        z[b * 128 + j] += sm / (float)k;
    }
}

// ---------------------------------------------------------------------------
// SAGE round 2: proven gather + scalar transposed-weight epilogue (R10 form).
// ---------------------------------------------------------------------------
__global__ void k_sage_gather(const float* __restrict__ h, const int* __restrict__ off,
                              const int* __restrict__ csrc, const int* __restrict__ map,
                              const int* __restrict__ orig,
                              const float* __restrict__ WlT, const float* __restrict__ bl,
                              const float* __restrict__ WrT, const float* __restrict__ wp,
                              float* __restrict__ out, float* __restrict__ score, int ng) {
    __shared__ float sh[4][128];
    int blk = blockIdx.x;
    int g = blk & 7, i = blk >> 3;
    int wv = threadIdx.x >> 6, j = threadIdx.x & 63;
    int n = g * ng + i * 4 + wv;
    int o = orig[n];
    int beg = off[o], end = off[o + 1];
    float own = h[n * 64 + j];           // hoisted: overlaps edge resolution
    float acc = 0.f; int cnt = 0;
    for (int base = beg; base < end; base += 64) {
        int d = end - base; if (d > 64) d = 64;
        int cs = (j < d) ? map[csrc[base + j]] : -1;
        cnt += __popcll(__ballot(cs >= 0));
        int e = 0;
        for (; e + 8 <= d; e += 8) {
            int c0 = __shfl(cs, e),     c1 = __shfl(cs, e + 1);
            int c2 = __shfl(cs, e + 2), c3 = __shfl(cs, e + 3);
            int c4 = __shfl(cs, e + 4), c5 = __shfl(cs, e + 5);
            int c6 = __shfl(cs, e + 6), c7 = __shfl(cs, e + 7);
            float v0 = (c0 >= 0) ? h[c0 * 64 + j] : 0.f;
            float v1 = (c1 >= 0) ? h[c1 * 64 + j] : 0.f;
            float v2 = (c2 >= 0) ? h[c2 * 64 + j] : 0.f;
            float v3 = (c3 >= 0) ? h[c3 * 64 + j] : 0.f;
            float v4 = (c4 >= 0) ? h[c4 * 64 + j] : 0.f;
            float v5 = (c5 >= 0) ? h[c5 * 64 + j] : 0.f;
            float v6 = (c6 >= 0) ? h[c6 * 64 + j] : 0.f;
            float v7 = (c7 >= 0) ? h[c7 * 64 + j] : 0.f;
            acc += ((v0 + v1) + (v2 + v3)) + ((v4 + v5) + (v6 + v7));
        }
        for (; e + 4 <= d; e += 4) {
            int c0 = __shfl(cs, e),     c1 = __shfl(cs, e + 1);
            int c2 = __shfl(cs, e + 2), c3 = __shfl(cs, e + 3);
            float v0 = (c0 >= 0) ? h[c0 * 64 + j] : 0.f;
            float v1 = (c1 >= 0) ? h[c1 * 64 + j] : 0.f;
            float v2 = (c2 >= 0) ? h[c2 * 64 + j] : 0.f;
            float v3 = (c3 >= 0) ? h[c3 * 64 + j] : 0.f;
            acc += (v0 + v1) + (v2 + v3);
        }
        for (; e < d; e++) {
            int c0 = __shfl(cs, e);
            if (c0 >= 0) acc += h[c0 * 64 + j];
        }
    }
    sh[wv][j] = acc / fmaxf((float)cnt, 1.0f);
    sh[wv][64 + j] = own;
    __syncthreads();
    const float* sm = sh[wv];
    float v = bl[j];
    for (int q = 0; q < 64; q++)
        v += sm[q] * WlT[q * 64 + j] + sm[64 + q] * WrT[q * 64 + j];
    v = fmaxf(v, 0.f);
    out[n * 64 + j] = v;
    float wvp = wp[j];
    float d = v * wvp, ww = wvp * wvp;
    for (int o2 = 32; o2; o2 >>= 1) { d += __shfl_xor(d, o2); ww += __shfl_xor(ww, o2); }
    if (j == 0) score[n] = tanhf(d / sqrtf(ww));
}

// ---------------------------------------------------------------------------
// Fused GCN prologue: xw = h @ W.T (transposed weights via wave-private LDS
// broadcast) + live-neighbor count -> dis. Wave per node.
// ---------------------------------------------------------------------------
__global__ void k_xwdis(const float* __restrict__ h, const float* __restrict__ WT,
                        const int* __restrict__ off, const int* __restrict__ csrc,
                        const int* __restrict__ map, const int* __restrict__ orig,
                        float* __restrict__ xw, float* __restrict__ dis, int ng) {
    __shared__ float sh[4][64];
    int blk = blockIdx.x;
    int g = blk & 7, i = blk >> 3;
    int wv = threadIdx.x >> 6, j = threadIdx.x & 63;
    int n = g * ng + i * 4 + wv;
    sh[wv][j] = h[n * 64 + j];           // wave-private stage (same-wave LDS, in-order)
    int o = orig[n];
    int beg = off[o], end = off[o + 1];
    int c = 0;
    for (int base = beg; base < end; base += 64) {
        int d = end - base; if (d > 64) d = 64;
        int cs = (j < d) ? map[csrc[base + j]] : -1;
        c += __popcll(__ballot(cs >= 0));
    }
    const float* sm = sh[wv];
    float v = 0.f;
    for (int q = 0; q < 64; q++) v += sm[q] * WT[q * 64 + j];
    xw[n * 64 + j] = v;
    if (j == 0) dis[n] = 1.0f / sqrtf(1.0f + (float)c);
}

__global__ void k_gcn_gather(const float* __restrict__ xw, const int* __restrict__ off,
                             const int* __restrict__ csrc, const int* __restrict__ map,
                             const int* __restrict__ orig, const float* __restrict__ dis,
                             const float* __restrict__ bb, const float* __restrict__ wp,
                             float* __restrict__ out, float* __restrict__ score, int ng) {
    int blk = blockIdx.x;
    int g = blk & 7, i = blk >> 3;
    int wv = threadIdx.x >> 6, j = threadIdx.x & 63;
    int n = g * ng + i * 4 + wv;
    int o = orig[n];
    int beg = off[o], end = off[o + 1];
    float dn = dis[n];
    float own = xw[n * 64 + j];
    float acc = 0.f;
    for (int base = beg; base < end; base += 64) {
        int d = end - base; if (d > 64) d = 64;
        int cs = -1; float dsv = 0.f;
        if (j < d) {
            int cc = map[csrc[base + j]];
            if (cc >= 0) { cs = cc; dsv = dis[cc]; }
        }
        int e = 0;
        for (; e + 8 <= d; e += 8) {
            int c0 = __shfl(cs, e),     c1 = __shfl(cs, e + 1);
            int c2 = __shfl(cs, e + 2), c3 = __shfl(cs, e + 3);
            int c4 = __shfl(cs, e + 4), c5 = __shfl(cs, e + 5);
            int c6 = __shfl(cs, e + 6), c7 = __shfl(cs, e + 7);
            float d0 = __shfl(dsv, e),     d1 = __shfl(dsv, e + 1);
            float d2 = __shfl(dsv, e + 2), d3 = __shfl(dsv, e + 3);
            float d4 = __shfl(dsv, e + 4), d5 = __shfl(dsv, e + 5);
            float d6 = __shfl(dsv, e + 6), d7 = __shfl(dsv, e + 7);
            float v0 = (c0 >= 0) ? xw[c0 * 64 + j] * d0 : 0.f;
            float v1 = (c1 >= 0) ? xw[c1 * 64 + j] * d1 : 0.f;
            float v2 = (c2 >= 0) ? xw[c2 * 64 + j] * d2 : 0.f;
            float v3 = (c3 >= 0) ? xw[c3 * 64 + j] * d3 : 0.f;
            float v4 = (c4 >= 0) ? xw[c4 * 64 + j] * d4 : 0.f;
            float v5 = (c5 >= 0) ? xw[c5 * 64 + j] * d5 : 0.f;
            float v6 = (c6 >= 0) ? xw[c6 * 64 + j] * d6 : 0.f;
            float v7 = (c7 >= 0) ? xw[c7 * 64 + j] * d7 : 0.f;
            acc += ((v0 + v1) + (v2 + v3)) + ((v4 + v5) + (v6 + v7));
        }
        for (; e + 4 <= d; e += 4) {
            int c0 = __shfl(cs, e),     c1 = __shfl(cs, e + 1);
            int c2 = __shfl(cs, e + 2), c3 = __shfl(cs, e + 3);
            float d0 = __shfl(dsv, e),     d1 = __shfl(dsv, e + 1);
            float d2 = __shfl(dsv, e + 2), d3 = __shfl(dsv, e + 3);
            float v0 = (c0 >= 0) ? xw[c0 * 64 + j] * d0 : 0.f;
            float v1 = (c1 >= 0) ? xw[c1 * 64 + j] * d1 : 0.f;
            float v2 = (c2 >= 0) ? xw[c2 * 64 + j] * d2 : 0.f;
            float v3 = (c3 >= 0) ? xw[c3 * 64 + j] * d3 : 0.f;
            acc += (v0 + v1) + (v2 + v3);
        }
        for (; e < d; e++) {
            int c0 = __shfl(cs, e);
            float d0 = __shfl(dsv, e);
            if (c0 >= 0) acc += xw[c0 * 64 + j] * d0;
        }
    }
    float v = acc * dn + own * dn * dn + bb[j];
    v = fmaxf(v, 0.f);
    out[n * 64 + j] = v;
    float wvp = wp[j];
    float d = v * wvp, ww = wvp * wvp;
    for (int o2 = 32; o2; o2 >>= 1) { d += __shfl_xor(d, o2); ww += __shfl_xor(ww, o2); }
    if (j == 0) score[n] = tanhf(d / sqrtf(ww));
}

// ---------------------------------------------------------------------------
// Final MLP + softmax: 8 blocks, transposed (coalesced) weights
// ---------------------------------------------------------------------------
__global__ void k_mlp(const float* __restrict__ z,
                      const float* __restrict__ WaT, const float* __restrict__ ba,
                      const float* __restrict__ WbT, const float* __restrict__ bb,
                      const float* __restrict__ WcT, const float* __restrict__ bc,
                      float* __restrict__ out) {
    __shared__ float sz[128];
    __shared__ float sa[128];
    __shared__ float sb2[64];
    __shared__ float sc[256];
    __shared__ float tmp[256];
    __shared__ float wred[4];
    int b = blockIdx.x, t = threadIdx.x;
    if (t < 128) sz[t] = z[b * 128 + t];
    __syncthreads();
    {
        int o = t & 127, half = t >> 7;
        float v = 0.f;
        int q0 = half * 64;
        for (int q = q0; q < q0 + 64; q++) v += sz[q] * WaT[q * 128 + o];
        tmp[t] = v;
        __syncthreads();
        if (t < 128) sa[t] = fmaxf(tmp[t] + tmp[t + 128] + ba[t], 0.f);
        __syncthreads();
    }
    {
        int o = t & 63, qr = t >> 6;
        float v = 0.f;
        int q0 = qr * 32;
        for (int q = q0; q < q0 + 32; q++) v += sa[q] * WbT[q * 64 + o];
        tmp[t] = v;
        __syncthreads();
        if (t < 64) sb2[t] = fmaxf(tmp[t] + tmp[t + 64] + tmp[t + 128] + tmp[t + 192] + bb[t], 0.f);
        __syncthreads();
    }
    {
        float v = bc[t];
        for (int q = 0; q < 64; q++) v += sb2[q] * WcT[q * 256 + t];
        sc[t] = v;
    }
    __syncthreads();
    float m = sc[t];
    for (int o2 = 32; o2; o2 >>= 1) m = fmaxf(m, __shfl_xor(m, o2));
    if ((t & 63) == 0) wred[t >> 6] = m;
    __syncthreads();
    m = fmaxf(fmaxf(wred[0], wred[1]), fmaxf(wred[2], wred[3]));
    __syncthreads();
    float e = expf(sc[t] - m);
    float s = e;
    for (int o2 = 32; o2; o2 >>= 1) s += __shfl_xor(s, o2);
    if ((t & 63) == 0) wred[t >> 6] = s;
    __syncthreads();
    s = wred[0] + wred[1] + wred[2] + wred[3];
    out[b * 256 + t] = e / s;
}

// ---------------------------------------------------------------------------
extern "C" void kernel_launch(void* const* d_in, const int* in_sizes, int n_in,
                              void* d_out, int out_size, void* d_ws, size_t ws_size,
                              hipStream_t stream) {
    const float* x   = (const float*)d_in[0];
    const int*   ei  = (const int*)d_in[1];
    const int* src = ei;
    const int* dst = ei + Eq;
    const float* Wl1 = (const float*)d_in[2];
    const float* bl1 = (const float*)d_in[3];
    const float* Wr1 = (const float*)d_in[4];
    const float* Wl2 = (const float*)d_in[5];
    const float* bl2 = (const float*)d_in[6];
    const float* Wr2 = (const float*)d_in[7];
    const float* W4  = (const float*)d_in[8];
    const float* b4  = (const float*)d_in[9];
    const float* W5  = (const float*)d_in[10];
    const float* b5  = (const float*)d_in[11];
    const float* wp1 = (const float*)d_in[12];
    const float* wp2 = (const float*)d_in[13];
    const float* wp4 = (const float*)d_in[14];
    const float* wp5 = (const float*)d_in[15];
    const float* Wa  = (const float*)d_in[16];
    const float* ba  = (const float*)d_in[17];
    const float* Wb  = (const float*)d_in[18];
    const float* bbv = (const float*)d_in[19];
    const float* Wc  = (const float*)d_in[20];
    const float* bc  = (const float*)d_in[21];
    float* out = (float*)d_out;

    const int N1 = Nq / 2, N2 = Nq / 4, N3 = Nq / 8, N4 = Nq / 16;

    // workspace layout (~64 MB)
    char* w = (char*)d_ws;
    float* hA    = (float*)w; w += (size_t)Nq * 64 * 4;        // 33.5 MB
    float* hB    = (float*)w; w += (size_t)N1 * 64 * 4;        // 16.8 MB
    int*   csrc  = (int*)w;   w += (size_t)Eq * 4;             //  8.4 MB
    int*   coff  = (int*)w;   w += (size_t)(Nq + 1) * 4;
    int*   cursor= (int*)w;   w += (size_t)Nq * 4;
    int*   cnt   = (int*)w;   w += (size_t)Nq * 4;
    float* dis   = (float*)w; w += (size_t)Nq * 4;
    float* score = (float*)w; w += (size_t)Nq * 4;
    int*   newpos= (int*)w;   w += (size_t)Nq * 4;
    int*   map   = (int*)w;   w += (size_t)Nq * 4;
    int*   perm  = (int*)w;   w += (size_t)Nq * 4;
    int*   origA = (int*)w;   w += (size_t)Nq * 4;
    int*   origB = (int*)w;   w += (size_t)Nq * 4;
    int*   bsum  = (int*)w;   w += 512 * 4;
    float* part  = (float*)w; w += (size_t)8 * 64 * 128 * 4;   // 256 KB
    float* z     = (float*)w; w += 1024 * 4;
    float* wT    = (float*)w; w += 4 * 4096 * 4;               // 64 KB
    float* wMT   = (float*)w; w += (16384 + 8192 + 16384) * 4; // 160 KB
    float* WlT2 = wT, *WrT2 = wT + 4096, *W4T = wT + 8192, *W5T = wT + 12288;
    float* WaT = wMT, *WbT = wMT + 16384, *WcT = wMT + 16384 + 8192;

    // ---- One-time: weight transposes + CSR build
    k_wt4<<<4, 256, 0, stream>>>(Wl2, Wr2, W4, W5, wT);
    k_wtmlp<<<3, 256, 0, stream>>>(Wa, Wb, Wc, wMT);
    hipMemsetAsync(cnt, 0, (size_t)Nq * 4, stream);
    hipMemsetAsync(z, 0, 1024 * 4, stream);
    k_cnt<<<Eq / 256, 256, 0, stream>>>(dst, cnt);
    k_scan_a<<<512, 256, 0, stream>>>(cnt, bsum);
    k_scan_b<<<1, 512, 0, stream>>>(bsum);
    k_scan_c<<<512, 256, 0, stream>>>(cnt, bsum, coff, cursor);
    k_fill<<<Eq / 256, 256, 0, stream>>>(src, dst, cursor, csrc);

    // ---- Round 1: SAGE1(x) -> hA, pool -> hB [N1 x 64]
    k_sage1<<<Nq / 4, 256, 0, stream>>>(x, coff, csrc, Wl1, bl1, Wr1, wp1, hA, score);
    k_topk<16><<<8, 1024, 0, stream>>>(score, newpos, perm, map, 1);
    k_compact<<<N1 / 4, 256, 0, stream>>>(hA, score, perm, nullptr, origA, 1, hB, N1 / 8);
    k_readout_part<<<8 * 64, 256, 0, stream>>>(hB, part, NGq / 2, 64);
    k_readout_fin<<<4, 256, 0, stream>>>(part, z, NGq / 2, 64);

    // ---- Round 2: SAGE2(hB) -> hA, pool -> hB [N2 x 64]
    k_sage_gather<<<N1 / 4, 256, 0, stream>>>(hB, coff, csrc, map, origA,
                                              WlT2, bl2, WrT2, wp2, hA, score, N1 / 8);
    k_topk<8><<<8, 1024, 0, stream>>>(score, newpos, perm, map, 2);
    k_compact<<<N2 / 4, 256, 0, stream>>>(hA, score, perm, origA, origB, 0, hB, N2 / 8);
    k_readout_part<<<8 * 32, 256, 0, stream>>>(hB, part, NGq / 4, 32);
    k_readout_fin<<<4, 256, 0, stream>>>(part, z, NGq / 4, 32);

    // ---- Round 3: GCN W4(hB): xw+dis fused -> hA, out -> hA[N2*64:], pool -> hB
    k_xwdis<<<N2 / 4, 256, 0, stream>>>(hB, W4T, coff, csrc, map, origB, hA, dis, N2 / 8);
    k_gcn_gather<<<N2 / 4, 256, 0, stream>>>(hA, coff, csrc, map, origB, dis,
                                             b4, wp4, hA + (size_t)N2 * 64, score, N2 / 8);
    k_topk<4><<<8, 1024, 0, stream>>>(score, newpos, perm, map, 2);
    k_compact<<<N3 / 4, 256, 0, stream>>>(hA + (size_t)N2 * 64, score, perm,
                                          origB, origA, 0, hB, N3 / 8);
    k_readout_part<<<8 * 16, 256, 0, stream>>>(hB, part, NGq / 8, 16);
    k_readout_fin<<<4, 256, 0, stream>>>(part, z, NGq / 8, 16);

    // ---- Round 4: GCN W5(hB): xw+dis fused -> hA, out -> hA[N3*64:], pool -> hB
    k_xwdis<<<N3 / 4, 256, 0, stream>>>(hB, W5T, coff, csrc, map, origA, hA, dis, N3 / 8);
    k_gcn_gather<<<N3 / 4, 256, 0, stream>>>(hA, coff, csrc, map, origA, dis,
                                             b5, wp5, hA + (size_t)N3 * 64, score, N3 / 8);
    k_topk<2><<<8, 1024, 0, stream>>>(score, newpos, perm, map, 0);
    k_compact<<<N4 / 4, 256, 0, stream>>>(hA + (size_t)N3 * 64, score, perm,
                                          origA, origB, 0, hB, N4 / 8);
    k_readout_part<<<8 * 8, 256, 0, stream>>>(hB, part, NGq / 16, 8);
    k_readout_fin<<<4, 256, 0, stream>>>(part, z, NGq / 16, 8);

    // ---- MLP + softmax
    k_mlp<<<8, 256, 0, stream>>>(z, WaT, ba, WbT, bbv, WcT, bc, out);
}